// Round 5
// baseline (285.312 us; speedup 1.0000x reference)
//
#include <hip/hip_runtime.h>
#include <math.h>

// Problem constants
#define C_DIM 512
#define NHEAD 8
#define HDIM 64
#define NTOK 8000
#define BN_TOK 16000

typedef __attribute__((ext_vector_type(8))) _Float16 f16x8;
typedef __attribute__((ext_vector_type(4))) float f32x4;
typedef __attribute__((ext_vector_type(2))) _Float16 h2;
typedef unsigned short u16;

__device__ __forceinline__ int imin(int a, int b) { return a < b ? a : b; }

// fp32 -> f16 (RNE)
__device__ __forceinline__ u16 f2h(float x) {
    _Float16 h = (_Float16)x;
    return __builtin_bit_cast(u16, h);
}

// async global->LDS, 16 bytes per lane (global_load_lds_dwordx4)
__device__ __forceinline__ void async16(const void* g, void* l) {
    __builtin_amdgcn_global_load_lds(
        (const __attribute__((address_space(1))) void*)g,
        (__attribute__((address_space(3))) void*)l, 16, 0, 0);
}

// R13: compiler-proof 16B global load. asm volatile cannot be sunk or
// reordered vs other volatile asm -> issue order is pinned; the counted
// vmcnt waits below rely on that. No auto-waitcnt is generated for the
// result, so EVERY consumption must be behind an explicit VMWAIT.
__device__ __forceinline__ f32x4 agload16(const u16* p) {
    f32x4 r;
    asm volatile("global_load_dwordx4 %0, %1, off" : "=v"(r) : "v"(p));
    return r;
}

// counted vmcnt + scheduler fence (rule #18: MFMA hoists past bare asm
// waitcnt; sched_barrier(0) immediately after is the required fence)
#define VMWAIT(N) do { asm volatile("s_waitcnt vmcnt(" #N ")"); \
                       __builtin_amdgcn_sched_barrier(0); } while (0)

// ---------------------------------------------------------------------------
// f_kv (B,C,N) fp32 -> kvT (B,N,C) f16. Fixed 512 x 8000 per batch.
// ---------------------------------------------------------------------------
__global__ __launch_bounds__(256) void transpose_c2l_f16(
    const float* __restrict__ in, u16* __restrict__ out)
{
    __shared__ float tile[32][33];
    int b = blockIdx.z;
    const float* inb = in + (size_t)b * 512 * NTOK;
    u16* outb = out + (size_t)b * NTOK * 512;
    int s0 = blockIdx.x * 32, r0 = blockIdx.y * 32;   // s: token, r: channel
    int tx = threadIdx.x & 31, ty = threadIdx.x >> 5;
#pragma unroll
    for (int i = 0; i < 4; i++)
        tile[ty + i * 8][tx] = inb[(size_t)(r0 + ty + i * 8) * NTOK + s0 + tx];
    __syncthreads();
    int rq = threadIdx.x & 7, sy = threadIdx.x >> 3;  // rq: channel quad, sy: token
    ushort4 o;
    o.x = f2h(tile[rq * 4 + 0][sy]);
    o.y = f2h(tile[rq * 4 + 1][sy]);
    o.z = f2h(tile[rq * 4 + 2][sy]);
    o.w = f2h(tile[rq * 4 + 3][sy]);
    *reinterpret_cast<ushort4*>(outb + (size_t)(s0 + sy) * 512 + r0 + rq * 4) = o;
}

// ---------------------------------------------------------------------------
// Merged weight converts: z selects which W (512 x Nout) fp32 -> (Npad x 512)
// f16, pad rows zeroed. Grid (16,16,5); small weights early-out on x.
// ---------------------------------------------------------------------------
__global__ __launch_bounds__(256) void wcvt_all(
    const float* __restrict__ W0, u16* __restrict__ T0,
    const float* __restrict__ W1, u16* __restrict__ T1,
    const float* __restrict__ W2, u16* __restrict__ T2,
    const float* __restrict__ W3, u16* __restrict__ T3,
    const float* __restrict__ W4, u16* __restrict__ T4)
{
    const float* W; u16* Wt; int Nout, Npad;
    switch (blockIdx.z) {
        case 0: W = W0; Wt = T0; Nout = 512; Npad = 512; break;
        case 1: W = W1; Wt = T1; Nout = 512; Npad = 512; break;
        case 2: W = W2; Wt = T2; Nout = 512; Npad = 512; break;
        case 3: W = W3; Wt = T3; Nout = 96;  Npad = 128; break;
        default: W = W4; Wt = T4; Nout = 32; Npad = 128; break;
    }
    int n0 = blockIdx.x * 32, k0 = blockIdx.y * 32;
    if (n0 >= Npad) return;
    __shared__ float t[32][33];
    int tx = threadIdx.x & 31, ty = threadIdx.x >> 5;
#pragma unroll
    for (int i = 0; i < 4; i++) {
        int k = k0 + ty + i * 8, n = n0 + tx;
        t[ty + i * 8][tx] = (n < Nout) ? W[(size_t)k * Nout + n] : 0.f;
    }
    __syncthreads();
#pragma unroll
    for (int i = 0; i < 4; i++) {
        int n = n0 + ty + i * 8, k = k0 + tx;
        Wt[(size_t)n * 512 + k] = f2h(t[tx][ty + i * 8]);
    }
}

// ---------------------------------------------------------------------------
// Fused LayerNorm + (B,C,N)->(B,N,C) transpose, LDS-tiled; f16 output.
// ---------------------------------------------------------------------------
__global__ __launch_bounds__(256) void ln_fused(
    const float* __restrict__ fq, const float* __restrict__ gamma,
    const float* __restrict__ beta, u16* __restrict__ q)
{
    __shared__ float tile[512][33];   // [c][t], 67.6 KB
    __shared__ float ps[32][17], pq[32][17];
    __shared__ float muA[32], rsA[32];
    int blk = blockIdx.x;
    int b = blk / 250;
    int n0 = (blk - b * 250) * 32;
    const float* src = fq + (size_t)b * C_DIM * NTOK + n0;
    int tid = threadIdx.x;
    int cgrp = tid >> 4;          // 0..15
    int tp = (tid & 15) * 2;      // 0,2,..,30
    float s0 = 0.f, q0 = 0.f, s1 = 0.f, q1 = 0.f;
#pragma unroll 4
    for (int it = 0; it < 32; ++it) {
        int c = it * 16 + cgrp;
        float2 v = *reinterpret_cast<const float2*>(src + (size_t)c * NTOK + tp);
        tile[c][tp] = v.x; tile[c][tp + 1] = v.y;
        s0 += v.x; q0 += v.x * v.x;
        s1 += v.y; q1 += v.y * v.y;
    }
    ps[tp][cgrp] = s0; pq[tp][cgrp] = q0;
    ps[tp + 1][cgrp] = s1; pq[tp + 1][cgrp] = q1;
    int lane = tid & 63, wv = tid >> 6;
    float4 g0 = *reinterpret_cast<const float4*>(gamma + lane * 4);
    float4 be0 = *reinterpret_cast<const float4*>(beta + lane * 4);
    float4 g1 = *reinterpret_cast<const float4*>(gamma + 256 + lane * 4);
    float4 be1 = *reinterpret_cast<const float4*>(beta + 256 + lane * 4);
    __syncthreads();
    if (tid < 32) {
        float S = 0.f, SQ = 0.f;
#pragma unroll
        for (int g = 0; g < 16; ++g) { S += ps[tid][g]; SQ += pq[tid][g]; }
        float mu = S * (1.f / 512.f);
        float var = SQ * (1.f / 512.f) - mu * mu;
        muA[tid] = mu;
        rsA[tid] = rsqrtf(var + 1e-5f);
    }
    __syncthreads();
#pragma unroll
    for (int it = 0; it < 16; ++it) {
        int task = it * 4 + wv;     // 0..63 : (token, half)
        int t = task >> 1, h = task & 1;
        int c0 = h * 256 + lane * 4;
        float mu = muA[t], rs = rsA[t];
        float4 g = h ? g1 : g0, bb = h ? be1 : be0;
        ushort4 o;
        o.x = f2h((tile[c0 + 0][t] - mu) * rs * g.x + bb.x);
        o.y = f2h((tile[c0 + 1][t] - mu) * rs * g.y + bb.y);
        o.z = f2h((tile[c0 + 2][t] - mu) * rs * g.z + bb.z);
        o.w = f2h((tile[c0 + 3][t] - mu) * rs * g.w + bb.w);
        *reinterpret_cast<ushort4*>(q + ((size_t)(b * NTOK + n0 + t)) * C_DIM + c0) = o;
    }
}

// ---------------------------------------------------------------------------
// R13: weight-stationary GEMM + ASM-PINNED software pipeline.
// R12 post-mortem: C++ ring buffer was collapsed by the compiler (VGPR
// stayed 52 -> loads re-sunk next to uses -> serial load/wait/MFMA, 7%
// MfmaUtil). Fix: A-fragment loads are inline-asm global_load_dwordx4
// (un-sinkable), issued 3 batches ahead; each MFMA cluster is behind a
// COUNTED s_waitcnt vmcnt(12/8/4/0) + sched_barrier(0) (rule #18 fence).
// 12 loads stay in flight at steady state -- the T4 "never drain to 0"
// pattern at register level. B-frags remain compiler-scheduled ds_reads
// from the 64KB resident panel (lgkmcnt handling is near-optimal per m97).
// Same barrier-free M-loop, 8-wave blocks, XOR seg swizzle, XCD decode.
// outKind 0: fp32 row-major [token*ldc + col]
// outKind 1: f16  row-major [token*512 + col] (+optional relu)
// outKind 2: fp32 transposed (B,C,N): [(b*512+col)*8000 + tok], float4 store
// ---------------------------------------------------------------------------
__device__ __forceinline__ void ws_body512(
    const u16* __restrict__ A, const u16* __restrict__ Bp,
    const float* __restrict__ bias, float* __restrict__ Cf,
    u16* __restrict__ Ch, int colBase, int colValid, int ldc,
    int outKind, int relu, int mt)
{
    __shared__ u16 Bs[64 * 512];   // 64 KB
    int tid = threadIdx.x, lane = tid & 63, wv = tid >> 6;   // wv 0..7

    // stage weight panel: 4096 x 16B chunks, 8 per thread.
    // LDS linear slot (row,seg) <- global k-segment (seg ^ (row&7)).
#pragma unroll
    for (int c = 0; c < 8; c++) {
        int id = c * 512 + tid;
        int row = id >> 6, seg = id & 63;
        async16(Bp + (size_t)row * 512 + ((seg ^ (row & 7)) << 3),
                Bs + (size_t)id * 8);
    }

    int ml = lane & 15, quad = lane >> 4;
    int wm = (wv >> 1) * 64, wn = (wv & 1) * 32;   // 4x2 wave grid, 256x64

    int rowj[2];
#pragma unroll
    for (int j = 0; j < 2; j++) rowj[j] = wn + j * 16 + ml;

    __syncthreads();   // panel resident; compiler drains vmcnt(0) here, so
                       // the counted waits below start from a clean slate

    int bm = mt * 256;
    const u16* Ap = A + ((size_t)(bm + wm + ml)) * 512 + quad * 8;

    f32x4 acc[4][2];
#pragma unroll
    for (int i = 0; i < 4; i++)
#pragma unroll
        for (int j = 0; j < 2; j++) acc[i][j] = (f32x4){0.f, 0.f, 0.f, 0.f};

    f32x4 afr[4][4];   // A-frag ring [batch&3][i], raw 16B
    f16x8 bf[2][2];    // B-frag ring [kk&1][j]

    // prologue: issue batches 0..2 (12 loads in flight)
#pragma unroll
    for (int kb = 0; kb < 3; kb++)
#pragma unroll
        for (int i = 0; i < 4; i++)
            afr[kb][i] = agload16(Ap + (size_t)i * 16 * 512 + kb * 32);
#pragma unroll
    for (int j = 0; j < 2; j++)
        bf[0][j] = *reinterpret_cast<const f16x8*>(
            Bs + (size_t)rowj[j] * 512 + (((0 + quad) ^ (rowj[j] & 7)) << 3));

#pragma unroll
    for (int kk = 0; kk < 16; kk++) {
        // issue batch kk+3 (keeps 12 outstanding at steady state)
        if (kk + 3 < 16) {
#pragma unroll
            for (int i = 0; i < 4; i++)
                afr[(kk + 3) & 3][i] = agload16(
                    Ap + (size_t)i * 16 * 512 + (kk + 3) * 32);
        }
        // prefetch next B-frags (LDS, compiler-managed lgkmcnt)
        if (kk + 1 < 16) {
#pragma unroll
            for (int j = 0; j < 2; j++) {
                int seg = (kk + 1) * 4 + quad;
                bf[(kk + 1) & 1][j] = *reinterpret_cast<const f16x8*>(
                    Bs + (size_t)rowj[j] * 512 + ((seg ^ (rowj[j] & 7)) << 3));
            }
        }
        // wait ONLY for batch kk: 3 newer batches may stay in flight
        if (kk < 13)      VMWAIT(12);
        else if (kk == 13) VMWAIT(8);
        else if (kk == 14) VMWAIT(4);
        else               VMWAIT(0);
#pragma unroll
        for (int i = 0; i < 4; i++)
#pragma unroll
            for (int j = 0; j < 2; j++)
                acc[i][j] = __builtin_amdgcn_mfma_f32_16x16x32_f16(
                    __builtin_bit_cast(f16x8, afr[kk & 3][i]),
                    bf[kk & 1][j], acc[i][j], 0, 0, 0);
    }

    // epilogue: C/D layout col=lane&15, row=quad*4+reg (m89/m91).
    // all asm loads drained by VMWAIT(0) at kk=15.
#pragma unroll
    for (int i = 0; i < 4; i++) {
        int row = bm + wm + i * 16 + quad * 4;   // token index (4 consec)
        if (row >= BN_TOK) continue;             // tail tile (mt=62) guard
#pragma unroll
        for (int j = 0; j < 2; j++) {
            int col = colBase + wn + j * 16 + ml;
            if (col < colValid) {
                float bia = bias[col];
                if (outKind == 2) {
                    int bb = row >= 8000;
                    float4 st;
                    st.x = acc[i][j][0] + bia;
                    st.y = acc[i][j][1] + bia;
                    st.z = acc[i][j][2] + bia;
                    st.w = acc[i][j][3] + bia;
                    *reinterpret_cast<float4*>(
                        Cf + ((size_t)(bb * 512 + col)) * 8000
                           + (row - bb * 8000)) = st;
                } else if (outKind == 1) {
#pragma unroll
                    for (int rg = 0; rg < 4; rg++) {
                        float v = acc[i][j][rg] + bia;
                        if (relu) v = fmaxf(v, 0.f);
                        Ch[(size_t)(row + rg) * 512 + col] = f2h(v);
                    }
                } else {
#pragma unroll
                    for (int rg = 0; rg < 4; rg++)
                        Cf[(size_t)(row + rg) * ldc + col] =
                            acc[i][j][rg] + bia;
                }
            }
        }
    }
}

// 512 flat blocks = 8 panels x 64 M-groups (256 rows each; m=63 -> exit),
// decoded so the 8 panel-blocks sharing one A-slab get the same (did & 7)
// -> same XCD (A is the 8x-reread operand; keep rereads in one L2).
__global__ __launch_bounds__(512, 4) void gemm_ws_big(
    const u16* __restrict__ A, const u16* __restrict__ WT,
    const float* __restrict__ bias, float* __restrict__ Cf,
    u16* __restrict__ Ch, int outKind, int relu)
{
    int did = blockIdx.x;                      // 0..511
    int m = ((did >> 6) << 3) | (did & 7);     // M-group 0..63
    if (m >= 63) return;                       // 63 tiles of 256 cover 16000
    int p = (did >> 3) & 7;                    // panel 0..7
    ws_body512(A, WT + (size_t)p * 64 * 512, bias, Cf, Ch,
               p * 64, 512, 512, outKind, relu, m);
}

// dual: y=0 off cols 0..63, y=1 off cols 64..95 (padded panel rows 64..127),
// y=2 logits cols 0..31. Grid (63, 3).
__global__ __launch_bounds__(512, 4) void gemm_ws_dual(
    const u16* __restrict__ hid, const u16* __restrict__ Wo2T,
    const float* __restrict__ bo2, float* __restrict__ offb,
    const u16* __restrict__ Qb, const u16* __restrict__ WaT,
    const float* __restrict__ ba, float* __restrict__ lgb)
{
    int y = blockIdx.y, mt = blockIdx.x;
    const u16* A; const u16* Bp; const float* bias; float* Cf;
    int colBase, colValid, ldc;
    if (y == 0) { A = hid; Bp = Wo2T;            bias = bo2; Cf = offb; colBase = 0;  colValid = 96; ldc = 96; }
    else if (y == 1) { A = hid; Bp = Wo2T + 64 * 512; bias = bo2; Cf = offb; colBase = 64; colValid = 96; ldc = 96; }
    else { A = Qb; Bp = WaT;             bias = ba;  Cf = lgb;  colBase = 0;  colValid = 32; ldc = 32; }
    ws_body512(A, Bp, bias, Cf, nullptr, colBase, colValid, ldc, 0, 0, mt);
}

// ---------------------------------------------------------------------------
// Fused softmax + offset clip + trilinear sample + einsum, f16 volume.
// One wave = one token (8 heads); lane = h*8 + cl, 8 channels/lane via one
// uint4 (8 x f16) corner load. Channels accumulate as 4 x h2 via
// v_pk_fma_f16 (2 ch/inst). p-loop NOT unrolled (R6: full unroll -> 132
// VGPR -> 9% occ). 32-bit element offsets.
// XCD swizzle: blockIdx.x & 7 -> 2000-token contiguous slab per XCD.
// Reference quirk: off-ch0 -> W(x) axis, ch1 -> H(y), ch2 -> D(z); H=W=D=20
// collapses normalization to clip(base+off, 0, 19).
// ---------------------------------------------------------------------------
__global__ __launch_bounds__(256) void sample_kernel(
    const u16* __restrict__ vol, const float* __restrict__ offb,
    const float* __restrict__ lgb, u16* __restrict__ outp)
{
    int wid = threadIdx.x >> 6, lane = threadIdx.x & 63;
    int bx = blockIdx.x;                               // 4000 = 8 slabs x 500
    int bn = ((bx & 7) * 500 + (bx >> 3)) * 4 + wid;   // token 0..15999
    int h = lane >> 3, cl = lane & 7;
    int b = bn / NTOK, n = bn - b * NTOK;
    int y = n / 400;
    int r2 = n - y * 400;
    int x = r2 / 20;
    int z = r2 - x * 20;

    const float* op = offb + (size_t)bn * 96 + h * 12;
    const float* lp = lgb + (size_t)bn * 32 + h * 4;
    float l0 = lp[0], l1 = lp[1], l2 = lp[2], l3 = lp[3];
    float mx = fmaxf(fmaxf(l0, l1), fmaxf(l2, l3));
    float e0 = expf(l0 - mx), e1 = expf(l1 - mx), e2 = expf(l2 - mx), e3 = expf(l3 - mx);
    float inv = 1.f / (e0 + e1 + e2 + e3);
    float at[4] = {e0 * inv, e1 * inv, e2 * inv, e3 * inv};

    const u16* volb = vol + b * (NTOK * C_DIM) + h * HDIM + cl * 8;
    h2 acc0 = (h2)(_Float16)0, acc1 = acc0, acc2 = acc0, acc3 = acc0;
#pragma unroll 1
    for (int p = 0; p < 4; p++) {
        float o0 = fminf(fmaxf(op[p * 3 + 0], -3.f), 3.f);
        float o1 = fminf(fmaxf(op[p * 3 + 1], -3.f), 3.f);
        float o2 = fminf(fmaxf(op[p * 3 + 2], -3.f), 3.f);
        float ix = fminf(fmaxf((float)y + o0, 0.f), 19.f);  // W axis
        float iy = fminf(fmaxf((float)x + o1, 0.f), 19.f);  // H axis
        float iz = fminf(fmaxf((float)z + o2, 0.f), 19.f);  // D axis
        float xf = floorf(ix), yf = floorf(iy), zf = floorf(iz);
        float fx = ix - xf, fy = iy - yf, fz = iz - zf;
        int x0 = (int)xf, y0 = (int)yf, z0 = (int)zf;
        int x1 = imin(x0 + 1, 19), y1 = imin(y0 + 1, 19), z1 = imin(z0 + 1, 19);
        // spatial = yi*400 + xi*20 + zi, channels contiguous (stride C_DIM)
        int s00 = y0 * 400 + x0 * 20, s01 = y0 * 400 + x1 * 20;
        int s10 = y1 * 400 + x0 * 20, s11 = y1 * 400 + x1 * 20;
        uint4 v000 = *(const uint4*)(volb + (s00 + z0) * C_DIM);
        uint4 v001 = *(const uint4*)(volb + (s01 + z0) * C_DIM);
        uint4 v010 = *(const uint4*)(volb + (s10 + z0) * C_DIM);
        uint4 v011 = *(const uint4*)(volb + (s11 + z0) * C_DIM);
        uint4 v100 = *(const uint4*)(volb + (s00 + z1) * C_DIM);
        uint4 v101 = *(const uint4*)(volb + (s01 + z1) * C_DIM);
        uint4 v110 = *(const uint4*)(volb + (s10 + z1) * C_DIM);
        uint4 v111 = *(const uint4*)(volb + (s11 + z1) * C_DIM);
        float wz0 = (1.f - fz) * at[p], wz1 = fz * at[p];
        float w00 = wz0 * (1.f - fy), w01 = wz0 * fy;
        float w10 = wz1 * (1.f - fy), w11 = wz1 * fy;
        float gx0 = 1.f - fx;
        float cw[8] = { w00 * gx0, w00 * fx, w01 * gx0, w01 * fx,
                        w10 * gx0, w10 * fx, w11 * gx0, w11 * fx };
        const uint4* cv[8] = { &v000, &v001, &v010, &v011,
                               &v100, &v101, &v110, &v111 };
#pragma unroll
        for (int c = 0; c < 8; c++) {
            _Float16 wh = (_Float16)cw[c];
            h2 w2; w2.x = wh; w2.y = wh;
            uint4 d = *cv[c];
            acc0 += __builtin_bit_cast(h2, d.x) * w2;
            acc1 += __builtin_bit_cast(h2, d.y) * w2;
            acc2 += __builtin_bit_cast(h2, d.z) * w2;
            acc3 += __builtin_bit_cast(h2, d.w) * w2;
        }
    }
    uint4 o;
    o.x = __builtin_bit_cast(unsigned, acc0);
    o.y = __builtin_bit_cast(unsigned, acc1);
    o.z = __builtin_bit_cast(unsigned, acc2);
    o.w = __builtin_bit_cast(unsigned, acc3);
    *reinterpret_cast<uint4*>(outp + (size_t)bn * C_DIM + h * HDIM + cl * 8) = o;
}

// ---------------------------------------------------------------------------
// Launch
// ---------------------------------------------------------------------------
extern "C" void kernel_launch(void* const* d_in, const int* in_sizes, int n_in,
                              void* d_out, int out_size, void* d_ws, size_t ws_size,
                              hipStream_t stream)
{
    const float* f_query = (const float*)d_in[0];
    const float* f_kv    = (const float*)d_in[1];
    const float* ln_g    = (const float*)d_in[2];
    const float* ln_b    = (const float*)d_in[3];
    const float* Wq      = (const float*)d_in[4];
    const float* bq      = (const float*)d_in[5];
    const float* Wo1     = (const float*)d_in[6];
    const float* bo1     = (const float*)d_in[7];
    const float* Wo2     = (const float*)d_in[8];
    const float* bo2     = (const float*)d_in[9];
    const float* Wa      = (const float*)d_in[10];
    const float* ba      = (const float*)d_in[11];
    const float* Wout    = (const float*)d_in[12];
    const float* bout    = (const float*)d_in[13];
    float* out = (float*)d_out;

    float* ws = (float*)d_ws;
    float* offb = ws;                     // 1,536,000 f
    float* lgb  = ws + 1536000;           //   512,000 f
    u16* kvT   = (u16*)(ws + 2048000);    // 16000x512 (f16 channels-last)
    u16* qb    = kvT  + 8192000;          // 16000x512 (q; later sampled)
    u16* Qb    = qb   + 8192000;          // 16000x512
    u16* hid   = Qb   + 8192000;          // 16000x512
    u16* WqT   = hid  + 8192000;          // 512x512
    u16* Wo1T  = WqT + 262144;
    u16* WoutT = Wo1T + 262144;
    u16* Wo2T  = WoutT + 262144;          // 128x512 (96 valid, pad 0)
    u16* WaT   = Wo2T + 65536;            // 128x512 (32 valid, pad 0)
    // total ~75.6 MiB

    dim3 blk(256);
    dim3 blk512(512);
    // all weight transpose-converts in one dispatch (fp32 -> f16 N^T x K)
    wcvt_all<<<dim3(16, 16, 5), blk, 0, stream>>>(
        Wq, WqT, Wo1, Wo1T, Wout, WoutT, Wo2, Wo2T, Wa, WaT);
    // f_kv (B,C,N) fp32 -> kvT (B,N,C) f16
    transpose_c2l_f16<<<dim3(250, 16, 2), blk, 0, stream>>>(f_kv, kvT);
    // q = LN(transpose(f_query)) -> f16, fused LDS tile
    ln_fused<<<dim3(500), blk, 0, stream>>>(f_query, ln_g, ln_b, qb);
    // Q = q @ Wq + bq -> f16
    gemm_ws_big<<<dim3(512), blk512, 0, stream>>>(qb, WqT, bq, nullptr, Qb, 1, 0);
    // hidden = relu(Q @ Wo1 + bo1) -> f16
    gemm_ws_big<<<dim3(512), blk512, 0, stream>>>(Qb, Wo1T, bo1, nullptr, hid, 1, 1);
    // off = hidden @ Wo2 + bo2 (fp32) AND logits = Q @ Wa + ba (fp32)
    gemm_ws_dual<<<dim3(63, 3), blk512, 0, stream>>>(
        hid, Wo2T, bo2, offb, Qb, WaT, ba, lgb);
    // fused sample/softmax/einsum -> qb (f16, raw h2 store)
    sample_kernel<<<dim3(4000), blk, 0, stream>>>(kvT, offb, lgb, qb);
    // out(B,C,N) = (sampled @ Wout + bout)^T : tokens=M, channels=N, float4 st
    gemm_ws_big<<<dim3(512), blk512, 0, stream>>>(qb, WoutT, bout, out, nullptr, 2, 0);
}

// Round 6
// 230.131 us; speedup vs baseline: 1.2398x; 1.2398x over previous
//
#include <hip/hip_runtime.h>
#include <math.h>

// Problem constants
#define C_DIM 512
#define NHEAD 8
#define HDIM 64
#define NTOK 8000
#define BN_TOK 16000

typedef __attribute__((ext_vector_type(8))) _Float16 f16x8;
typedef __attribute__((ext_vector_type(4))) float f32x4;
typedef __attribute__((ext_vector_type(2))) _Float16 h2;
typedef unsigned short u16;

__device__ __forceinline__ int imin(int a, int b) { return a < b ? a : b; }

// fp32 -> f16 (RNE)
__device__ __forceinline__ u16 f2h(float x) {
    _Float16 h = (_Float16)x;
    return __builtin_bit_cast(u16, h);
}

// R14: MFMA-fragment-major blocked layout for ALL GEMM A-matrices
// (qb/Qb/hid/sampled). u16 index for (token t, channel c):
//   [t>>4][c>>5][(c>>3)&3][t&15][c&7]  (block 16 tok x 512 ch = 8192 u16)
// A wave's 16x16x32 A-frag (rows rb*16+ml, cols kk*32+quad*8..+8) is then
// base + lane*8 u16 -> ONE fully-coalesced 1KB global_load_dwordx4.
// R13 post-mortem: divergent 1KB-stride A loads cost ~16x TA time; that —
// not latency depth — capped MfmaUtil at 7%.
__device__ __forceinline__ size_t aidx(int t, int c) {
    return ((size_t)(t >> 4)) * 8192 + (size_t)((c >> 5) * 512
         + (((c >> 3) & 3) * 128) + ((t & 15) * 8) + (c & 7));
}

// async global->LDS, 16 bytes per lane (global_load_lds_dwordx4)
__device__ __forceinline__ void async16(const void* g, void* l) {
    __builtin_amdgcn_global_load_lds(
        (const __attribute__((address_space(1))) void*)g,
        (__attribute__((address_space(3))) void*)l, 16, 0, 0);
}

// compiler-proof 16B global load (asm volatile: un-sinkable, issue-ordered)
__device__ __forceinline__ f32x4 agload16(const u16* p) {
    f32x4 r;
    asm volatile("global_load_dwordx4 %0, %1, off" : "=v"(r) : "v"(p));
    return r;
}

// counted vmcnt + scheduler fence (rule #18)
#define VMWAIT(N) do { asm volatile("s_waitcnt vmcnt(" #N ")"); \
                       __builtin_amdgcn_sched_barrier(0); } while (0)

// ---------------------------------------------------------------------------
// f_kv (B,C,N) fp32 -> kvT (B,N,C) f16. Fixed 512 x 8000 per batch.
// (kvT keeps channels-contiguous row-major: consumed only by sample gather.)
// ---------------------------------------------------------------------------
__global__ __launch_bounds__(256) void transpose_c2l_f16(
    const float* __restrict__ in, u16* __restrict__ out)
{
    __shared__ float tile[32][33];
    int b = blockIdx.z;
    const float* inb = in + (size_t)b * 512 * NTOK;
    u16* outb = out + (size_t)b * NTOK * 512;
    int s0 = blockIdx.x * 32, r0 = blockIdx.y * 32;   // s: token, r: channel
    int tx = threadIdx.x & 31, ty = threadIdx.x >> 5;
#pragma unroll
    for (int i = 0; i < 4; i++)
        tile[ty + i * 8][tx] = inb[(size_t)(r0 + ty + i * 8) * NTOK + s0 + tx];
    __syncthreads();
    int rq = threadIdx.x & 7, sy = threadIdx.x >> 3;  // rq: channel quad, sy: token
    ushort4 o;
    o.x = f2h(tile[rq * 4 + 0][sy]);
    o.y = f2h(tile[rq * 4 + 1][sy]);
    o.z = f2h(tile[rq * 4 + 2][sy]);
    o.w = f2h(tile[rq * 4 + 3][sy]);
    *reinterpret_cast<ushort4*>(outb + (size_t)(s0 + sy) * 512 + r0 + rq * 4) = o;
}

// ---------------------------------------------------------------------------
// Merged weight converts: z selects which W (512 x Nout) fp32 -> (Npad x 512)
// f16, pad rows zeroed. Grid (16,16,5); small weights early-out on x.
// ---------------------------------------------------------------------------
__global__ __launch_bounds__(256) void wcvt_all(
    const float* __restrict__ W0, u16* __restrict__ T0,
    const float* __restrict__ W1, u16* __restrict__ T1,
    const float* __restrict__ W2, u16* __restrict__ T2,
    const float* __restrict__ W3, u16* __restrict__ T3,
    const float* __restrict__ W4, u16* __restrict__ T4)
{
    const float* W; u16* Wt; int Nout, Npad;
    switch (blockIdx.z) {
        case 0: W = W0; Wt = T0; Nout = 512; Npad = 512; break;
        case 1: W = W1; Wt = T1; Nout = 512; Npad = 512; break;
        case 2: W = W2; Wt = T2; Nout = 512; Npad = 512; break;
        case 3: W = W3; Wt = T3; Nout = 96;  Npad = 128; break;
        default: W = W4; Wt = T4; Nout = 32; Npad = 128; break;
    }
    int n0 = blockIdx.x * 32, k0 = blockIdx.y * 32;
    if (n0 >= Npad) return;
    __shared__ float t[32][33];
    int tx = threadIdx.x & 31, ty = threadIdx.x >> 5;
#pragma unroll
    for (int i = 0; i < 4; i++) {
        int k = k0 + ty + i * 8, n = n0 + tx;
        t[ty + i * 8][tx] = (n < Nout) ? W[(size_t)k * Nout + n] : 0.f;
    }
    __syncthreads();
#pragma unroll
    for (int i = 0; i < 4; i++) {
        int n = n0 + ty + i * 8, k = k0 + tx;
        Wt[(size_t)n * 512 + k] = f2h(t[tx][ty + i * 8]);
    }
}

// ---------------------------------------------------------------------------
// Fused LayerNorm + (B,C,N)->(B,N,C) transpose; f16 output in BLOCKED layout.
// ---------------------------------------------------------------------------
__global__ __launch_bounds__(256) void ln_fused(
    const float* __restrict__ fq, const float* __restrict__ gamma,
    const float* __restrict__ beta, u16* __restrict__ q)
{
    __shared__ float tile[512][33];   // [c][t], 67.6 KB
    __shared__ float ps[32][17], pq[32][17];
    __shared__ float muA[32], rsA[32];
    int blk = blockIdx.x;
    int b = blk / 250;
    int n0 = (blk - b * 250) * 32;
    const float* src = fq + (size_t)b * C_DIM * NTOK + n0;
    int tid = threadIdx.x;
    int cgrp = tid >> 4;          // 0..15
    int tp = (tid & 15) * 2;      // 0,2,..,30
    float s0 = 0.f, q0 = 0.f, s1 = 0.f, q1 = 0.f;
#pragma unroll 4
    for (int it = 0; it < 32; ++it) {
        int c = it * 16 + cgrp;
        float2 v = *reinterpret_cast<const float2*>(src + (size_t)c * NTOK + tp);
        tile[c][tp] = v.x; tile[c][tp + 1] = v.y;
        s0 += v.x; q0 += v.x * v.x;
        s1 += v.y; q1 += v.y * v.y;
    }
    ps[tp][cgrp] = s0; pq[tp][cgrp] = q0;
    ps[tp + 1][cgrp] = s1; pq[tp + 1][cgrp] = q1;
    int lane = tid & 63, wv = tid >> 6;
    float4 g0 = *reinterpret_cast<const float4*>(gamma + lane * 4);
    float4 be0 = *reinterpret_cast<const float4*>(beta + lane * 4);
    float4 g1 = *reinterpret_cast<const float4*>(gamma + 256 + lane * 4);
    float4 be1 = *reinterpret_cast<const float4*>(beta + 256 + lane * 4);
    __syncthreads();
    if (tid < 32) {
        float S = 0.f, SQ = 0.f;
#pragma unroll
        for (int g = 0; g < 16; ++g) { S += ps[tid][g]; SQ += pq[tid][g]; }
        float mu = S * (1.f / 512.f);
        float var = SQ * (1.f / 512.f) - mu * mu;
        muA[tid] = mu;
        rsA[tid] = rsqrtf(var + 1e-5f);
    }
    __syncthreads();
#pragma unroll
    for (int it = 0; it < 16; ++it) {
        int task = it * 4 + wv;     // 0..63 : (token, half)
        int t = task >> 1, h = task & 1;
        int c0 = h * 256 + lane * 4;
        float mu = muA[t], rs = rsA[t];
        float4 g = h ? g1 : g0, bb = h ? be1 : be0;
        ushort4 o;
        o.x = f2h((tile[c0 + 0][t] - mu) * rs * g.x + bb.x);
        o.y = f2h((tile[c0 + 1][t] - mu) * rs * g.y + bb.y);
        o.z = f2h((tile[c0 + 2][t] - mu) * rs * g.z + bb.z);
        o.w = f2h((tile[c0 + 3][t] - mu) * rs * g.w + bb.w);
        // blocked layout; c0 % 8 in {0,4} -> ushort4 stays in one 8-group
        *reinterpret_cast<ushort4*>(q + aidx(b * NTOK + n0 + t, c0)) = o;
    }
}

// ---------------------------------------------------------------------------
// R14: weight-stationary GEMM, blocked-A (coalesced frag loads) + asm ring.
// A-frag load = base + lane*16B, one 1KB contiguous dwordx4 per (i,kk).
// Ring: 3 batches ahead (12 in flight), counted vmcnt(12/8/4/0) +
// sched_barrier fences. B-frags ds_read from 64KB resident panel (XOR
// seg swizzle). Barrier-free M-loop, 8-wave blocks, XCD-chunked decode.
// outKind 0: fp32 row-major [token*ldc + col]
// outKind 1: f16 BLOCKED (aidx) (+optional relu)
// outKind 2: fp32 transposed (B,C,N): [(b*512+col)*8000 + tok], float4 store
// ---------------------------------------------------------------------------
__device__ __forceinline__ void ws_body512(
    const u16* __restrict__ A, const u16* __restrict__ Bp,
    const float* __restrict__ bias, float* __restrict__ Cf,
    u16* __restrict__ Ch, int colBase, int colValid, int ldc,
    int outKind, int relu, int mt)
{
    __shared__ u16 Bs[64 * 512];   // 64 KB
    int tid = threadIdx.x, lane = tid & 63, wv = tid >> 6;   // wv 0..7

    // stage weight panel: 4096 x 16B chunks, 8 per thread.
#pragma unroll
    for (int c = 0; c < 8; c++) {
        int id = c * 512 + tid;
        int row = id >> 6, seg = id & 63;
        async16(Bp + (size_t)row * 512 + ((seg ^ (row & 7)) << 3),
                Bs + (size_t)id * 8);
    }

    int ml = lane & 15, quad = lane >> 4;
    int wm = (wv >> 1) * 64, wn = (wv & 1) * 32;   // 4x2 wave grid, 256x64

    int rowj[2];
#pragma unroll
    for (int j = 0; j < 2; j++) rowj[j] = wn + j * 16 + ml;

    __syncthreads();   // panel resident; vmcnt drained -> counts start clean

    int bm = mt * 256;
    // blocked-A: row-block (bm+wm)/16, per-lane 16B slot
    const u16* Ap = A + ((size_t)((bm + wm) >> 4)) * 8192 + (size_t)lane * 8;

    f32x4 acc[4][2];
#pragma unroll
    for (int i = 0; i < 4; i++)
#pragma unroll
        for (int j = 0; j < 2; j++) acc[i][j] = (f32x4){0.f, 0.f, 0.f, 0.f};

    f32x4 afr[4][4];   // A-frag ring [batch&3][i]
    f16x8 bf[2][2];    // B-frag ring [kk&1][j]

    // prologue: issue batches 0..2 (12 loads in flight)
#pragma unroll
    for (int kb = 0; kb < 3; kb++)
#pragma unroll
        for (int i = 0; i < 4; i++)
            afr[kb][i] = agload16(Ap + (size_t)i * 8192 + kb * 512);
#pragma unroll
    for (int j = 0; j < 2; j++)
        bf[0][j] = *reinterpret_cast<const f16x8*>(
            Bs + (size_t)rowj[j] * 512 + (((0 + quad) ^ (rowj[j] & 7)) << 3));

#pragma unroll
    for (int kk = 0; kk < 16; kk++) {
        if (kk + 3 < 16) {
#pragma unroll
            for (int i = 0; i < 4; i++)
                afr[(kk + 3) & 3][i] = agload16(
                    Ap + (size_t)i * 8192 + (kk + 3) * 512);
        }
        if (kk + 1 < 16) {
#pragma unroll
            for (int j = 0; j < 2; j++) {
                int seg = (kk + 1) * 4 + quad;
                bf[(kk + 1) & 1][j] = *reinterpret_cast<const f16x8*>(
                    Bs + (size_t)rowj[j] * 512 + ((seg ^ (rowj[j] & 7)) << 3));
            }
        }
        if (kk < 13)      VMWAIT(12);
        else if (kk == 13) VMWAIT(8);
        else if (kk == 14) VMWAIT(4);
        else               VMWAIT(0);
#pragma unroll
        for (int i = 0; i < 4; i++)
#pragma unroll
            for (int j = 0; j < 2; j++)
                acc[i][j] = __builtin_amdgcn_mfma_f32_16x16x32_f16(
                    __builtin_bit_cast(f16x8, afr[kk & 3][i]),
                    bf[kk & 1][j], acc[i][j], 0, 0, 0);
    }

    // epilogue: C/D layout col=lane&15, row=quad*4+reg (m89/m91).
#pragma unroll
    for (int i = 0; i < 4; i++) {
        int row = bm + wm + i * 16 + quad * 4;   // token index (4 consec)
        if (row >= BN_TOK) continue;             // tail tile (mt=62) guard
#pragma unroll
        for (int j = 0; j < 2; j++) {
            int col = colBase + wn + j * 16 + ml;
            if (col < colValid) {
                float bia = bias[col];
                if (outKind == 2) {
                    int bb = row >= 8000;
                    float4 st;
                    st.x = acc[i][j][0] + bia;
                    st.y = acc[i][j][1] + bia;
                    st.z = acc[i][j][2] + bia;
                    st.w = acc[i][j][3] + bia;
                    *reinterpret_cast<float4*>(
                        Cf + ((size_t)(bb * 512 + col)) * 8000
                           + (row - bb * 8000)) = st;
                } else if (outKind == 1) {
#pragma unroll
                    for (int rg = 0; rg < 4; rg++) {
                        float v = acc[i][j][rg] + bia;
                        if (relu) v = fmaxf(v, 0.f);
                        Ch[aidx(row + rg, col)] = f2h(v);   // blocked store
                    }
                } else {
#pragma unroll
                    for (int rg = 0; rg < 4; rg++)
                        Cf[(size_t)(row + rg) * ldc + col] =
                            acc[i][j][rg] + bia;
                }
            }
        }
    }
}

// 512 flat blocks = 8 panels x 64 M-groups (256 rows each; m=63 -> exit),
// decoded so the 8 panel-blocks sharing one A-slab get the same (did & 7)
// -> same XCD (A is the 8x-reread operand; keep rereads in one L2).
__global__ __launch_bounds__(512, 4) void gemm_ws_big(
    const u16* __restrict__ A, const u16* __restrict__ WT,
    const float* __restrict__ bias, float* __restrict__ Cf,
    u16* __restrict__ Ch, int outKind, int relu)
{
    int did = blockIdx.x;                      // 0..511
    int m = ((did >> 6) << 3) | (did & 7);     // M-group 0..63
    if (m >= 63) return;                       // 63 tiles of 256 cover 16000
    int p = (did >> 3) & 7;                    // panel 0..7
    ws_body512(A, WT + (size_t)p * 64 * 512, bias, Cf, Ch,
               p * 64, 512, 512, outKind, relu, m);
}

// dual: y=0 off cols 0..63, y=1 off cols 64..95 (padded panel rows 64..127),
// y=2 logits cols 0..31. Grid (63, 3).
__global__ __launch_bounds__(512, 4) void gemm_ws_dual(
    const u16* __restrict__ hid, const u16* __restrict__ Wo2T,
    const float* __restrict__ bo2, float* __restrict__ offb,
    const u16* __restrict__ Qb, const u16* __restrict__ WaT,
    const float* __restrict__ ba, float* __restrict__ lgb)
{
    int y = blockIdx.y, mt = blockIdx.x;
    const u16* A; const u16* Bp; const float* bias; float* Cf;
    int colBase, colValid, ldc;
    if (y == 0) { A = hid; Bp = Wo2T;            bias = bo2; Cf = offb; colBase = 0;  colValid = 96; ldc = 96; }
    else if (y == 1) { A = hid; Bp = Wo2T + 64 * 512; bias = bo2; Cf = offb; colBase = 64; colValid = 96; ldc = 96; }
    else { A = Qb; Bp = WaT;             bias = ba;  Cf = lgb;  colBase = 0;  colValid = 32; ldc = 32; }
    ws_body512(A, Bp, bias, Cf, nullptr, colBase, colValid, ldc, 0, 0, mt);
}

// ---------------------------------------------------------------------------
// Fused softmax + offset clip + trilinear sample + einsum, f16 volume.
// Output (sampled) now stored in BLOCKED layout (consumed as A by out-GEMM).
// ---------------------------------------------------------------------------
__global__ __launch_bounds__(256) void sample_kernel(
    const u16* __restrict__ vol, const float* __restrict__ offb,
    const float* __restrict__ lgb, u16* __restrict__ outp)
{
    int wid = threadIdx.x >> 6, lane = threadIdx.x & 63;
    int bx = blockIdx.x;                               // 4000 = 8 slabs x 500
    int bn = ((bx & 7) * 500 + (bx >> 3)) * 4 + wid;   // token 0..15999
    int h = lane >> 3, cl = lane & 7;
    int b = bn / NTOK, n = bn - b * NTOK;
    int y = n / 400;
    int r2 = n - y * 400;
    int x = r2 / 20;
    int z = r2 - x * 20;

    const float* op = offb + (size_t)bn * 96 + h * 12;
    const float* lp = lgb + (size_t)bn * 32 + h * 4;
    float l0 = lp[0], l1 = lp[1], l2 = lp[2], l3 = lp[3];
    float mx = fmaxf(fmaxf(l0, l1), fmaxf(l2, l3));
    float e0 = expf(l0 - mx), e1 = expf(l1 - mx), e2 = expf(l2 - mx), e3 = expf(l3 - mx);
    float inv = 1.f / (e0 + e1 + e2 + e3);
    float at[4] = {e0 * inv, e1 * inv, e2 * inv, e3 * inv};

    const u16* volb = vol + b * (NTOK * C_DIM) + h * HDIM + cl * 8;
    h2 acc0 = (h2)(_Float16)0, acc1 = acc0, acc2 = acc0, acc3 = acc0;
#pragma unroll 1
    for (int p = 0; p < 4; p++) {
        float o0 = fminf(fmaxf(op[p * 3 + 0], -3.f), 3.f);
        float o1 = fminf(fmaxf(op[p * 3 + 1], -3.f), 3.f);
        float o2 = fminf(fmaxf(op[p * 3 + 2], -3.f), 3.f);
        float ix = fminf(fmaxf((float)y + o0, 0.f), 19.f);  // W axis
        float iy = fminf(fmaxf((float)x + o1, 0.f), 19.f);  // H axis
        float iz = fminf(fmaxf((float)z + o2, 0.f), 19.f);  // D axis
        float xf = floorf(ix), yf = floorf(iy), zf = floorf(iz);
        float fx = ix - xf, fy = iy - yf, fz = iz - zf;
        int x0 = (int)xf, y0 = (int)yf, z0 = (int)zf;
        int x1 = imin(x0 + 1, 19), y1 = imin(y0 + 1, 19), z1 = imin(z0 + 1, 19);
        // spatial = yi*400 + xi*20 + zi, channels contiguous (stride C_DIM)
        int s00 = y0 * 400 + x0 * 20, s01 = y0 * 400 + x1 * 20;
        int s10 = y1 * 400 + x0 * 20, s11 = y1 * 400 + x1 * 20;
        uint4 v000 = *(const uint4*)(volb + (s00 + z0) * C_DIM);
        uint4 v001 = *(const uint4*)(volb + (s01 + z0) * C_DIM);
        uint4 v010 = *(const uint4*)(volb + (s10 + z0) * C_DIM);
        uint4 v011 = *(const uint4*)(volb + (s11 + z0) * C_DIM);
        uint4 v100 = *(const uint4*)(volb + (s00 + z1) * C_DIM);
        uint4 v101 = *(const uint4*)(volb + (s01 + z1) * C_DIM);
        uint4 v110 = *(const uint4*)(volb + (s10 + z1) * C_DIM);
        uint4 v111 = *(const uint4*)(volb + (s11 + z1) * C_DIM);
        float wz0 = (1.f - fz) * at[p], wz1 = fz * at[p];
        float w00 = wz0 * (1.f - fy), w01 = wz0 * fy;
        float w10 = wz1 * (1.f - fy), w11 = wz1 * fy;
        float gx0 = 1.f - fx;
        float cw[8] = { w00 * gx0, w00 * fx, w01 * gx0, w01 * fx,
                        w10 * gx0, w10 * fx, w11 * gx0, w11 * fx };
        const uint4* cv[8] = { &v000, &v001, &v010, &v011,
                               &v100, &v101, &v110, &v111 };
#pragma unroll
        for (int c = 0; c < 8; c++) {
            _Float16 wh = (_Float16)cw[c];
            h2 w2; w2.x = wh; w2.y = wh;
            uint4 d = *cv[c];
            acc0 += __builtin_bit_cast(h2, d.x) * w2;
            acc1 += __builtin_bit_cast(h2, d.y) * w2;
            acc2 += __builtin_bit_cast(h2, d.z) * w2;
            acc3 += __builtin_bit_cast(h2, d.w) * w2;
        }
    }
    uint4 o;
    o.x = __builtin_bit_cast(unsigned, acc0);
    o.y = __builtin_bit_cast(unsigned, acc1);
    o.z = __builtin_bit_cast(unsigned, acc2);
    o.w = __builtin_bit_cast(unsigned, acc3);
    // blocked store: c = h*64 + cl*8, 16B aligned slot
    *reinterpret_cast<uint4*>(outp + aidx(bn, h * HDIM + cl * 8)) = o;
}

// ---------------------------------------------------------------------------
// Launch
// ---------------------------------------------------------------------------
extern "C" void kernel_launch(void* const* d_in, const int* in_sizes, int n_in,
                              void* d_out, int out_size, void* d_ws, size_t ws_size,
                              hipStream_t stream)
{
    const float* f_query = (const float*)d_in[0];
    const float* f_kv    = (const float*)d_in[1];
    const float* ln_g    = (const float*)d_in[2];
    const float* ln_b    = (const float*)d_in[3];
    const float* Wq      = (const float*)d_in[4];
    const float* bq      = (const float*)d_in[5];
    const float* Wo1     = (const float*)d_in[6];
    const float* bo1     = (const float*)d_in[7];
    const float* Wo2     = (const float*)d_in[8];
    const float* bo2     = (const float*)d_in[9];
    const float* Wa      = (const float*)d_in[10];
    const float* ba      = (const float*)d_in[11];
    const float* Wout    = (const float*)d_in[12];
    const float* bout    = (const float*)d_in[13];
    float* out = (float*)d_out;

    float* ws = (float*)d_ws;
    float* offb = ws;                     // 1,536,000 f
    float* lgb  = ws + 1536000;           //   512,000 f
    u16* kvT   = (u16*)(ws + 2048000);    // 16000x512 (f16 channels-last)
    u16* qb    = kvT  + 8192000;          // 16000x512 (blocked; later sampled)
    u16* Qb    = qb   + 8192000;          // 16000x512 (blocked)
    u16* hid   = Qb   + 8192000;          // 16000x512 (blocked)
    u16* WqT   = hid  + 8192000;          // 512x512
    u16* Wo1T  = WqT + 262144;
    u16* WoutT = Wo1T + 262144;
    u16* Wo2T  = WoutT + 262144;          // 128x512 (96 valid, pad 0)
    u16* WaT   = Wo2T + 65536;            // 128x512 (32 valid, pad 0)
    // total ~75.6 MiB

    dim3 blk(256);
    dim3 blk512(512);
    // all weight transpose-converts in one dispatch (fp32 -> f16 N^T x K)
    wcvt_all<<<dim3(16, 16, 5), blk, 0, stream>>>(
        Wq, WqT, Wo1, Wo1T, Wout, WoutT, Wo2, Wo2T, Wa, WaT);
    // f_kv (B,C,N) fp32 -> kvT (B,N,C) f16
    transpose_c2l_f16<<<dim3(250, 16, 2), blk, 0, stream>>>(f_kv, kvT);
    // q = LN(transpose(f_query)) -> f16 blocked
    ln_fused<<<dim3(500), blk, 0, stream>>>(f_query, ln_g, ln_b, qb);
    // Q = q @ Wq + bq -> f16 blocked
    gemm_ws_big<<<dim3(512), blk512, 0, stream>>>(qb, WqT, bq, nullptr, Qb, 1, 0);
    // hidden = relu(Q @ Wo1 + bo1) -> f16 blocked
    gemm_ws_big<<<dim3(512), blk512, 0, stream>>>(Qb, Wo1T, bo1, nullptr, hid, 1, 1);
    // off = hidden @ Wo2 + bo2 (fp32) AND logits = Q @ Wa + ba (fp32)
    gemm_ws_dual<<<dim3(63, 3), blk512, 0, stream>>>(
        hid, Wo2T, bo2, offb, Qb, WaT, ba, lgb);
    // fused sample/softmax/einsum -> qb (f16 blocked)
    sample_kernel<<<dim3(4000), blk, 0, stream>>>(kvT, offb, lgb, qb);
    // out(B,C,N) = (sampled @ Wout + bout)^T : tokens=M, channels=N, float4 st
    gemm_ws_big<<<dim3(512), blk512, 0, stream>>>(qb, WoutT, bout, out, nullptr, 2, 0);
}

// Round 7
// 215.671 us; speedup vs baseline: 1.3229x; 1.0670x over previous
//
#include <hip/hip_runtime.h>
#include <math.h>

// Problem constants
#define C_DIM 512
#define NHEAD 8
#define HDIM 64
#define NTOK 8000
#define BN_TOK 16000

typedef __attribute__((ext_vector_type(8))) _Float16 f16x8;
typedef __attribute__((ext_vector_type(4))) float f32x4;
typedef __attribute__((ext_vector_type(2))) _Float16 h2;
typedef unsigned short u16;

__device__ __forceinline__ int imin(int a, int b) { return a < b ? a : b; }

// fp32 -> f16 (RNE)
__device__ __forceinline__ u16 f2h(float x) {
    _Float16 h = (_Float16)x;
    return __builtin_bit_cast(u16, h);
}

// MFMA-fragment-major blocked layout (R14, proven): token-major matrices.
// u16 index for (token t, channel c): block 16 tok x 512 ch = 8192 u16;
// a wave's 16x16x32 A-frag = base + lane*8 u16 -> one coalesced 1KB dwordx4.
__device__ __forceinline__ size_t aidx(int t, int c) {
    return ((size_t)(t >> 4)) * 8192 + (size_t)((c >> 5) * 512
         + (((c >> 3) & 3) * 128) + ((t & 15) * 8) + (c & 7));
}
// Same layout for weights as B-operand: (out-col n, k). Wave's B-frag for
// col-block cb, k-step kk = Wblk + cb*8192 + kk*512 + lane*8 (coalesced 1KB).
__device__ __forceinline__ size_t bidx(int n, int k) {
    return ((size_t)(n >> 4)) * 8192 + (size_t)((k >> 5) * 512
         + (((k >> 3) & 3) * 128) + ((n & 15) * 8) + (k & 7));
}

// async global->LDS, 16 bytes per lane (global_load_lds_dwordx4)
__device__ __forceinline__ void async16(const void* g, void* l) {
    __builtin_amdgcn_global_load_lds(
        (const __attribute__((address_space(1))) void*)g,
        (__attribute__((address_space(3))) void*)l, 16, 0, 0);
}

// compiler-proof 16B global load (asm volatile: un-sinkable, issue-ordered)
__device__ __forceinline__ f32x4 agload16(const u16* p) {
    f32x4 r;
    asm volatile("global_load_dwordx4 %0, %1, off" : "=v"(r) : "v"(p));
    return r;
}

// counted vmcnt + scheduler fence (rule #18). Extra compiler loads issued
// earlier only make the wait stricter (vmcnt drains in issue order) -> safe.
#define VMWAIT(N) do { asm volatile("s_waitcnt vmcnt(" #N ")"); \
                       __builtin_amdgcn_sched_barrier(0); } while (0)

// ---------------------------------------------------------------------------
// f_kv (B,C,N) fp32 -> kvT (B,N,C) f16. Fixed 512 x 8000 per batch.
// (kvT stays channels-contiguous row-major: consumed by sample gather.)
// ---------------------------------------------------------------------------
__global__ __launch_bounds__(256) void transpose_c2l_f16(
    const float* __restrict__ in, u16* __restrict__ out)
{
    __shared__ float tile[32][33];
    int b = blockIdx.z;
    const float* inb = in + (size_t)b * 512 * NTOK;
    u16* outb = out + (size_t)b * NTOK * 512;
    int s0 = blockIdx.x * 32, r0 = blockIdx.y * 32;   // s: token, r: channel
    int tx = threadIdx.x & 31, ty = threadIdx.x >> 5;
#pragma unroll
    for (int i = 0; i < 4; i++)
        tile[ty + i * 8][tx] = inb[(size_t)(r0 + ty + i * 8) * NTOK + s0 + tx];
    __syncthreads();
    int rq = threadIdx.x & 7, sy = threadIdx.x >> 3;  // rq: channel quad, sy: token
    ushort4 o;
    o.x = f2h(tile[rq * 4 + 0][sy]);
    o.y = f2h(tile[rq * 4 + 1][sy]);
    o.z = f2h(tile[rq * 4 + 2][sy]);
    o.w = f2h(tile[rq * 4 + 3][sy]);
    *reinterpret_cast<ushort4*>(outb + (size_t)(s0 + sy) * 512 + r0 + rq * 4) = o;
}

// ---------------------------------------------------------------------------
// Weight converts. z: 0 Wq(blocked) 1 Wo1(blocked) 2 Wout(FLAT N^T x K,
// staged to LDS by out-GEMM) 3 Wo2(blocked) 4 Wa(blocked). Pad rows zeroed.
// ---------------------------------------------------------------------------
__global__ __launch_bounds__(256) void wcvt_all(
    const float* __restrict__ W0, u16* __restrict__ T0,
    const float* __restrict__ W1, u16* __restrict__ T1,
    const float* __restrict__ W2, u16* __restrict__ T2,
    const float* __restrict__ W3, u16* __restrict__ T3,
    const float* __restrict__ W4, u16* __restrict__ T4)
{
    const float* W; u16* Wt; int Nout, Npad;
    switch (blockIdx.z) {
        case 0: W = W0; Wt = T0; Nout = 512; Npad = 512; break;
        case 1: W = W1; Wt = T1; Nout = 512; Npad = 512; break;
        case 2: W = W2; Wt = T2; Nout = 512; Npad = 512; break;
        case 3: W = W3; Wt = T3; Nout = 96;  Npad = 128; break;
        default: W = W4; Wt = T4; Nout = 32; Npad = 128; break;
    }
    int blocked = (blockIdx.z != 2);
    int n0 = blockIdx.x * 32, k0 = blockIdx.y * 32;
    if (n0 >= Npad) return;
    __shared__ float t[32][33];
    int tx = threadIdx.x & 31, ty = threadIdx.x >> 5;
#pragma unroll
    for (int i = 0; i < 4; i++) {
        int k = k0 + ty + i * 8, n = n0 + tx;
        t[ty + i * 8][tx] = (n < Nout) ? W[(size_t)k * Nout + n] : 0.f;
    }
    __syncthreads();
#pragma unroll
    for (int i = 0; i < 4; i++) {
        int n = n0 + ty + i * 8, k = k0 + tx;
        u16 v = f2h(t[tx][ty + i * 8]);
        if (blocked) Wt[bidx(n, k)] = v;
        else         Wt[(size_t)n * 512 + k] = v;
    }
}

// ---------------------------------------------------------------------------
// R15: FUSED MLP. The whole LN -> Q -> hid -> {off, logits} chain is
// token-local, so one block owns 64 tokens end-to-end. q and the ping-pong
// intermediate live in LDS ([64][520] u16 each: 520-pad = 16B-aligned rows
// + bank spread, no XOR needed); weights stream global->register via the
// R14-proven blocked layout + asm ring + counted vmcnt. Removes 3 dispatch
// boundaries and 3x 16.4MB intermediate HBM round-trips.
// 250 blocks x 512 thr, 137.7 KB LDS -> 1 block/CU, one generation.
// ---------------------------------------------------------------------------
// big LDS->LDS GEMM: wave wv: tg=wv&3 (16-token group), ch=wv>>2 (256-col
// half, as 4 groups of 64). B ring: 4 frags/batch, 3 ahead (12 in flight).
__device__ __forceinline__ void lds_gemm(
    const u16* Tin, u16* Tout, const u16* __restrict__ Wblk,
    const float* __restrict__ bias, int relu, int lane, int wv)
{
    int ml = lane & 15, quad = lane >> 4;
    int tg = wv & 3, ch = wv >> 2;
    const u16* Arow = Tin + (tg * 16 + ml) * 520;   // + (kk*4+quad)*8
#pragma unroll 1
    for (int cg = 0; cg < 4; ++cg) {
        int c0 = ch * 256 + cg * 64;
        const u16* Bp = Wblk + (size_t)(c0 >> 4) * 8192 + (size_t)lane * 8;
        f32x4 acc[4];
#pragma unroll
        for (int j = 0; j < 4; j++) acc[j] = (f32x4){0.f, 0.f, 0.f, 0.f};
        f32x4 bfr[4][4];   // ring [batch&3][j]
#pragma unroll
        for (int kb = 0; kb < 3; kb++)
#pragma unroll
            for (int j = 0; j < 4; j++)
                bfr[kb][j] = agload16(Bp + (size_t)j * 8192 + kb * 512);
#pragma unroll
        for (int kk = 0; kk < 16; kk++) {
            if (kk + 3 < 16) {
#pragma unroll
                for (int j = 0; j < 4; j++)
                    bfr[(kk + 3) & 3][j] = agload16(
                        Bp + (size_t)j * 8192 + (kk + 3) * 512);
            }
            f16x8 af = *reinterpret_cast<const f16x8*>(
                Arow + (kk * 4 + quad) * 8);
            if (kk < 13)       VMWAIT(12);
            else if (kk == 13) VMWAIT(8);
            else if (kk == 14) VMWAIT(4);
            else               VMWAIT(0);
#pragma unroll
            for (int j = 0; j < 4; j++)
                acc[j] = __builtin_amdgcn_mfma_f32_16x16x32_f16(
                    af, __builtin_bit_cast(f16x8, bfr[kk & 3][j]),
                    acc[j], 0, 0, 0);
        }
        // C/D: col=lane&15, row=quad*4+reg (m89/m91)
#pragma unroll
        for (int j = 0; j < 4; j++) {
            int col = c0 + j * 16 + ml;
            float bia = bias[col];
#pragma unroll
            for (int rg = 0; rg < 4; rg++) {
                float v = acc[j][rg] + bia;
                if (relu) v = fmaxf(v, 0.f);
                Tout[(tg * 16 + quad * 4 + rg) * 520 + col] = f2h(v);
            }
        }
    }
}

__global__ __launch_bounds__(512, 2) void mlp_fused(
    const float* __restrict__ fq, const float* __restrict__ gamma,
    const float* __restrict__ beta,
    const u16* __restrict__ Wqb, const float* __restrict__ bq,
    const u16* __restrict__ Wo1b, const float* __restrict__ bo1,
    const u16* __restrict__ Wo2b, const float* __restrict__ bo2,
    const u16* __restrict__ Wab, const float* __restrict__ ba,
    float* __restrict__ offb, float* __restrict__ lgb)
{
    __shared__ u16 T0[64 * 520], T1[64 * 520];     // 133.1 KB
    __shared__ float ps[64][8], pq[64][8];
    __shared__ float muA[64], rsA[64];
    int tid = threadIdx.x, lane = tid & 63, wv = tid >> 6;
    int blk = blockIdx.x;                // 250 blocks; 125 per batch (exact)
    int b = blk >= 125;
    int n0 = (blk - b * 125) * 64;
    int tp = tid & 63;
    const float* src = fq + (size_t)b * C_DIM * NTOK + n0 + tp;

    // ---- LN stats: thread (tp=token, wv=ch-group) over 64 channels ----
    {
        float s = 0.f, q = 0.f;
#pragma unroll 8
        for (int it = 0; it < 64; ++it) {
            float v = src[(size_t)(it * 8 + wv) * NTOK];
            s += v; q += v * v;
        }
        ps[tp][wv] = s; pq[tp][wv] = q;
    }
    __syncthreads();
    if (tid < 64) {
        float S = 0.f, SQ = 0.f;
#pragma unroll
        for (int g = 0; g < 8; ++g) { S += ps[tid][g]; SQ += pq[tid][g]; }
        float mu = S * (1.f / 512.f);
        muA[tid] = mu;
        rsA[tid] = rsqrtf(SQ * (1.f / 512.f) - mu * mu + 1e-5f);
    }
    __syncthreads();
    // ---- LN apply: re-read global (L2-warm), single f16 rounding -> T0 ----
    {
        float mu = muA[tp], rs = rsA[tp];
#pragma unroll 8
        for (int it = 0; it < 64; ++it) {
            int c = it * 8 + wv;
            float v = src[(size_t)c * NTOK];
            T0[tp * 520 + c] = f2h((v - mu) * rs * gamma[c] + beta[c]);
        }
    }
    __syncthreads();
    // ---- Q = q @ Wq + bq : T0 -> T1 ----
    lds_gemm(T0, T1, Wqb, bq, 0, lane, wv);
    __syncthreads();
    // ---- hid = relu(Q @ Wo1 + bo1) : T1 -> T0 ----
    lds_gemm(T1, T0, Wo1b, bo1, 1, lane, wv);
    __syncthreads();
    // ---- off (waves 0-5: hid@Wo2, 96 cols) & logits (waves 6-7: Q@Wa) ----
    {
        int ml = lane & 15, quad = lane >> 4;
        int isLg = wv >= 6;
        int cb = isLg ? (wv - 6) : wv;             // 16-col block
        const u16* Tin = isLg ? T1 : T0;
        const u16* Wsm = isLg ? Wab : Wo2b;
        const float* bs = isLg ? ba : bo2;
        float* outg = isLg ? lgb : offb;
        int ldo = isLg ? 32 : 96;
        // preload wave's full 16-col x 512-K weight panel to registers
        const u16* Wp = Wsm + (size_t)cb * 8192 + (size_t)lane * 8;
        f16x8 wb[16];
#pragma unroll
        for (int kk = 0; kk < 16; kk++)
            wb[kk] = *reinterpret_cast<const f16x8*>(Wp + (size_t)kk * 512);
        float bia = bs[cb * 16 + ml];
        int tbase = blk * 64;
#pragma unroll 1
        for (int tg = 0; tg < 4; tg++) {
            f32x4 acc = (f32x4){0.f, 0.f, 0.f, 0.f};
            const u16* Ar = Tin + (tg * 16 + ml) * 520;
#pragma unroll
            for (int kk = 0; kk < 16; kk++) {
                f16x8 af = *reinterpret_cast<const f16x8*>(
                    Ar + (kk * 4 + quad) * 8);
                acc = __builtin_amdgcn_mfma_f32_16x16x32_f16(
                    af, wb[kk], acc, 0, 0, 0);
            }
#pragma unroll
            for (int rg = 0; rg < 4; rg++)
                outg[(size_t)(tbase + tg * 16 + quad * 4 + rg) * ldo
                     + cb * 16 + ml] = acc[rg] + bia;
        }
    }
}

// ---------------------------------------------------------------------------
// Weight-stationary out-GEMM (R14, unchanged): blocked-A coalesced frag
// loads + asm ring + counted vmcnt; 64KB resident flat Wout panel.
// outKind 2: fp32 transposed (B,C,N): [(b*512+col)*8000 + tok], float4.
// ---------------------------------------------------------------------------
__device__ __forceinline__ void ws_body512(
    const u16* __restrict__ A, const u16* __restrict__ Bp,
    const float* __restrict__ bias, float* __restrict__ Cf,
    int colBase, int mt)
{
    __shared__ u16 Bs[64 * 512];   // 64 KB
    int tid = threadIdx.x, lane = tid & 63, wv = tid >> 6;   // wv 0..7

#pragma unroll
    for (int c = 0; c < 8; c++) {
        int id = c * 512 + tid;
        int row = id >> 6, seg = id & 63;
        async16(Bp + (size_t)row * 512 + ((seg ^ (row & 7)) << 3),
                Bs + (size_t)id * 8);
    }

    int ml = lane & 15, quad = lane >> 4;
    int wm = (wv >> 1) * 64, wn = (wv & 1) * 32;   // 4x2 wave grid, 256x64

    int rowj[2];
#pragma unroll
    for (int j = 0; j < 2; j++) rowj[j] = wn + j * 16 + ml;

    __syncthreads();   // panel resident; vmcnt drained -> counts start clean

    int bm = mt * 256;
    const u16* Ap = A + ((size_t)((bm + wm) >> 4)) * 8192 + (size_t)lane * 8;

    f32x4 acc[4][2];
#pragma unroll
    for (int i = 0; i < 4; i++)
#pragma unroll
        for (int j = 0; j < 2; j++) acc[i][j] = (f32x4){0.f, 0.f, 0.f, 0.f};

    f32x4 afr[4][4];
    f16x8 bf[2][2];

#pragma unroll
    for (int kb = 0; kb < 3; kb++)
#pragma unroll
        for (int i = 0; i < 4; i++)
            afr[kb][i] = agload16(Ap + (size_t)i * 8192 + kb * 512);
#pragma unroll
    for (int j = 0; j < 2; j++)
        bf[0][j] = *reinterpret_cast<const f16x8*>(
            Bs + (size_t)rowj[j] * 512 + (((0 + quad) ^ (rowj[j] & 7)) << 3));

#pragma unroll
    for (int kk = 0; kk < 16; kk++) {
        if (kk + 3 < 16) {
#pragma unroll
            for (int i = 0; i < 4; i++)
                afr[(kk + 3) & 3][i] = agload16(
                    Ap + (size_t)i * 8192 + (kk + 3) * 512);
        }
        if (kk + 1 < 16) {
#pragma unroll
            for (int j = 0; j < 2; j++) {
                int seg = (kk + 1) * 4 + quad;
                bf[(kk + 1) & 1][j] = *reinterpret_cast<const f16x8*>(
                    Bs + (size_t)rowj[j] * 512 + ((seg ^ (rowj[j] & 7)) << 3));
            }
        }
        if (kk < 13)       VMWAIT(12);
        else if (kk == 13) VMWAIT(8);
        else if (kk == 14) VMWAIT(4);
        else               VMWAIT(0);
#pragma unroll
        for (int i = 0; i < 4; i++)
#pragma unroll
            for (int j = 0; j < 2; j++)
                acc[i][j] = __builtin_amdgcn_mfma_f32_16x16x32_f16(
                    __builtin_bit_cast(f16x8, afr[kk & 3][i]),
                    bf[kk & 1][j], acc[i][j], 0, 0, 0);
    }

#pragma unroll
    for (int i = 0; i < 4; i++) {
        int row = bm + wm + i * 16 + quad * 4;   // token index (4 consec)
        if (row >= BN_TOK) continue;             // tail tile guard
#pragma unroll
        for (int j = 0; j < 2; j++) {
            int col = colBase + wn + j * 16 + ml;
            float bia = bias[col];
            int bb = row >= 8000;
            float4 st;
            st.x = acc[i][j][0] + bia;
            st.y = acc[i][j][1] + bia;
            st.z = acc[i][j][2] + bia;
            st.w = acc[i][j][3] + bia;
            *reinterpret_cast<float4*>(
                Cf + ((size_t)(bb * 512 + col)) * 8000 + (row - bb * 8000)) = st;
        }
    }
}

// 512 flat blocks = 8 panels x 64 M-groups; same-XCD decode for A-reuse.
__global__ __launch_bounds__(512, 4) void gemm_out(
    const u16* __restrict__ A, const u16* __restrict__ WT,
    const float* __restrict__ bias, float* __restrict__ Cf)
{
    int did = blockIdx.x;                      // 0..511
    int m = ((did >> 6) << 3) | (did & 7);     // M-group 0..63
    if (m >= 63) return;                       // 63 tiles of 256 cover 16000
    int p = (did >> 3) & 7;                    // panel 0..7
    ws_body512(A, WT + (size_t)p * 64 * 512, bias, Cf, p * 64, m);
}

// ---------------------------------------------------------------------------
// Fused softmax + offset clip + trilinear sample + einsum, f16 volume.
// Output (sampled) stored in BLOCKED layout (consumed as A by out-GEMM).
// ---------------------------------------------------------------------------
__global__ __launch_bounds__(256) void sample_kernel(
    const u16* __restrict__ vol, const float* __restrict__ offb,
    const float* __restrict__ lgb, u16* __restrict__ outp)
{
    int wid = threadIdx.x >> 6, lane = threadIdx.x & 63;
    int bx = blockIdx.x;                               // 4000 = 8 slabs x 500
    int bn = ((bx & 7) * 500 + (bx >> 3)) * 4 + wid;   // token 0..15999
    int h = lane >> 3, cl = lane & 7;
    int b = bn / NTOK, n = bn - b * NTOK;
    int y = n / 400;
    int r2 = n - y * 400;
    int x = r2 / 20;
    int z = r2 - x * 20;

    const float* op = offb + (size_t)bn * 96 + h * 12;
    const float* lp = lgb + (size_t)bn * 32 + h * 4;
    float l0 = lp[0], l1 = lp[1], l2 = lp[2], l3 = lp[3];
    float mx = fmaxf(fmaxf(l0, l1), fmaxf(l2, l3));
    float e0 = expf(l0 - mx), e1 = expf(l1 - mx), e2 = expf(l2 - mx), e3 = expf(l3 - mx);
    float inv = 1.f / (e0 + e1 + e2 + e3);
    float at[4] = {e0 * inv, e1 * inv, e2 * inv, e3 * inv};

    const u16* volb = vol + b * (NTOK * C_DIM) + h * HDIM + cl * 8;
    h2 acc0 = (h2)(_Float16)0, acc1 = acc0, acc2 = acc0, acc3 = acc0;
#pragma unroll 1
    for (int p = 0; p < 4; p++) {
        float o0 = fminf(fmaxf(op[p * 3 + 0], -3.f), 3.f);
        float o1 = fminf(fmaxf(op[p * 3 + 1], -3.f), 3.f);
        float o2 = fminf(fmaxf(op[p * 3 + 2], -3.f), 3.f);
        float ix = fminf(fmaxf((float)y + o0, 0.f), 19.f);  // W axis
        float iy = fminf(fmaxf((float)x + o1, 0.f), 19.f);  // H axis
        float iz = fminf(fmaxf((float)z + o2, 0.f), 19.f);  // D axis
        float xf = floorf(ix), yf = floorf(iy), zf = floorf(iz);
        float fx = ix - xf, fy = iy - yf, fz = iz - zf;
        int x0 = (int)xf, y0 = (int)yf, z0 = (int)zf;
        int x1 = imin(x0 + 1, 19), y1 = imin(y0 + 1, 19), z1 = imin(z0 + 1, 19);
        int s00 = y0 * 400 + x0 * 20, s01 = y0 * 400 + x1 * 20;
        int s10 = y1 * 400 + x0 * 20, s11 = y1 * 400 + x1 * 20;
        uint4 v000 = *(const uint4*)(volb + (s00 + z0) * C_DIM);
        uint4 v001 = *(const uint4*)(volb + (s01 + z0) * C_DIM);
        uint4 v010 = *(const uint4*)(volb + (s10 + z0) * C_DIM);
        uint4 v011 = *(const uint4*)(volb + (s11 + z0) * C_DIM);
        uint4 v100 = *(const uint4*)(volb + (s00 + z1) * C_DIM);
        uint4 v101 = *(const uint4*)(volb + (s01 + z1) * C_DIM);
        uint4 v110 = *(const uint4*)(volb + (s10 + z1) * C_DIM);
        uint4 v111 = *(const uint4*)(volb + (s11 + z1) * C_DIM);
        float wz0 = (1.f - fz) * at[p], wz1 = fz * at[p];
        float w00 = wz0 * (1.f - fy), w01 = wz0 * fy;
        float w10 = wz1 * (1.f - fy), w11 = wz1 * fy;
        float gx0 = 1.f - fx;
        float cw[8] = { w00 * gx0, w00 * fx, w01 * gx0, w01 * fx,
                        w10 * gx0, w10 * fx, w11 * gx0, w11 * fx };
        const uint4* cv[8] = { &v000, &v001, &v010, &v011,
                               &v100, &v101, &v110, &v111 };
#pragma unroll
        for (int c = 0; c < 8; c++) {
            _Float16 wh = (_Float16)cw[c];
            h2 w2; w2.x = wh; w2.y = wh;
            uint4 d = *cv[c];
            acc0 += __builtin_bit_cast(h2, d.x) * w2;
            acc1 += __builtin_bit_cast(h2, d.y) * w2;
            acc2 += __builtin_bit_cast(h2, d.z) * w2;
            acc3 += __builtin_bit_cast(h2, d.w) * w2;
        }
    }
    uint4 o;
    o.x = __builtin_bit_cast(unsigned, acc0);
    o.y = __builtin_bit_cast(unsigned, acc1);
    o.z = __builtin_bit_cast(unsigned, acc2);
    o.w = __builtin_bit_cast(unsigned, acc3);
    *reinterpret_cast<uint4*>(outp + aidx(bn, h * HDIM + cl * 8)) = o;
}

// ---------------------------------------------------------------------------
// Launch
// ---------------------------------------------------------------------------
extern "C" void kernel_launch(void* const* d_in, const int* in_sizes, int n_in,
                              void* d_out, int out_size, void* d_ws, size_t ws_size,
                              hipStream_t stream)
{
    const float* f_query = (const float*)d_in[0];
    const float* f_kv    = (const float*)d_in[1];
    const float* ln_g    = (const float*)d_in[2];
    const float* ln_b    = (const float*)d_in[3];
    const float* Wq      = (const float*)d_in[4];
    const float* bq      = (const float*)d_in[5];
    const float* Wo1     = (const float*)d_in[6];
    const float* bo1     = (const float*)d_in[7];
    const float* Wo2     = (const float*)d_in[8];
    const float* bo2     = (const float*)d_in[9];
    const float* Wa      = (const float*)d_in[10];
    const float* ba      = (const float*)d_in[11];
    const float* Wout    = (const float*)d_in[12];
    const float* bout    = (const float*)d_in[13];
    float* out = (float*)d_out;

    float* ws = (float*)d_ws;
    float* offb = ws;                     // 1,536,000 f
    float* lgb  = ws + 1536000;           //   512,000 f
    u16* kvT   = (u16*)(ws + 2048000);    // 16000x512 (f16 channels-last)
    u16* qb    = kvT  + 8192000;          // 16000x512 (blocked: sampled out)
    u16* WqT   = qb   + 8192000;          // 512x512 blocked
    u16* Wo1T  = WqT + 262144;            // 512x512 blocked
    u16* WoutT = Wo1T + 262144;           // 512x512 flat
    u16* Wo2T  = WoutT + 262144;          // 128x512 blocked (96 valid)
    u16* WaT   = Wo2T + 65536;            // 128x512 blocked (32 valid)

    dim3 blk(256);
    dim3 blk512(512);
    // weight converts (blocked for mlp; flat for Wout)
    wcvt_all<<<dim3(16, 16, 5), blk, 0, stream>>>(
        Wq, WqT, Wo1, Wo1T, Wout, WoutT, Wo2, Wo2T, Wa, WaT);
    // f_kv (B,C,N) fp32 -> kvT (B,N,C) f16
    transpose_c2l_f16<<<dim3(250, 16, 2), blk, 0, stream>>>(f_kv, kvT);
    // fused LN -> Q -> hid -> off/logits (token-local chain, one dispatch)
    mlp_fused<<<dim3(250), blk512, 0, stream>>>(
        f_query, ln_g, ln_b, WqT, bq, Wo1T, bo1, Wo2T, bo2, WaT, ba,
        offb, lgb);
    // fused sample/softmax/einsum -> qb (f16 blocked)
    sample_kernel<<<dim3(4000), blk, 0, stream>>>(kvT, offb, lgb, qb);
    // out(B,C,N) = (sampled @ Wout + bout)^T
    gemm_out<<<dim3(512), blk512, 0, stream>>>(qb, WoutT, bout, out);
}

// Round 8
// 202.802 us; speedup vs baseline: 1.4068x; 1.0635x over previous
//
#include <hip/hip_runtime.h>
#include <math.h>

// Problem constants
#define C_DIM 512
#define NHEAD 8
#define HDIM 64
#define NTOK 8000
#define BN_TOK 16000

typedef __attribute__((ext_vector_type(8))) _Float16 f16x8;
typedef __attribute__((ext_vector_type(4))) float f32x4;
typedef __attribute__((ext_vector_type(2))) _Float16 h2;
typedef unsigned short u16;

__device__ __forceinline__ int imin(int a, int b) { return a < b ? a : b; }

// fp32 -> f16 (RNE)
__device__ __forceinline__ u16 f2h(float x) {
    _Float16 h = (_Float16)x;
    return __builtin_bit_cast(u16, h);
}

// MFMA-fragment-major blocked layout (R14, proven): token-major matrices.
// u16 index for (token t, channel c): block 16 tok x 512 ch = 8192 u16;
// a wave's 16x16x32 A-frag = base + lane*8 u16 -> one coalesced 1KB dwordx4.
__device__ __forceinline__ size_t aidx(int t, int c) {
    return ((size_t)(t >> 4)) * 8192 + (size_t)((c >> 5) * 512
         + (((c >> 3) & 3) * 128) + ((t & 15) * 8) + (c & 7));
}
// Same layout for weights as B-operand: (out-col n, k). Wave's B-frag for
// col-block cb, k-step kk = Wblk + cb*8192 + kk*512 + lane*8 (coalesced 1KB).
__device__ __forceinline__ size_t bidx(int n, int k) {
    return ((size_t)(n >> 4)) * 8192 + (size_t)((k >> 5) * 512
         + (((k >> 3) & 3) * 128) + ((n & 15) * 8) + (k & 7));
}

// async global->LDS, 16 bytes per lane (global_load_lds_dwordx4)
__device__ __forceinline__ void async16(const void* g, void* l) {
    __builtin_amdgcn_global_load_lds(
        (const __attribute__((address_space(1))) void*)g,
        (__attribute__((address_space(3))) void*)l, 16, 0, 0);
}

// compiler-proof 16B global load (asm volatile: un-sinkable, issue-ordered)
__device__ __forceinline__ f32x4 agload16(const u16* p) {
    f32x4 r;
    asm volatile("global_load_dwordx4 %0, %1, off" : "=v"(r) : "v"(p));
    return r;
}

// counted vmcnt + scheduler fence (rule #18). Extra compiler loads issued
// earlier only make the wait stricter (vmcnt drains in issue order) -> safe.
#define VMWAIT(N) do { asm volatile("s_waitcnt vmcnt(" #N ")"); \
                       __builtin_amdgcn_sched_barrier(0); } while (0)

// ---------------------------------------------------------------------------
// f_kv (B,C,N) fp32 -> kvT (B,N,C) f16. Fixed 512 x 8000 per batch.
// (kvT stays channels-contiguous row-major: consumed by sample gather.)
// ---------------------------------------------------------------------------
__global__ __launch_bounds__(256) void transpose_c2l_f16(
    const float* __restrict__ in, u16* __restrict__ out)
{
    __shared__ float tile[32][33];
    int b = blockIdx.z;
    const float* inb = in + (size_t)b * 512 * NTOK;
    u16* outb = out + (size_t)b * NTOK * 512;
    int s0 = blockIdx.x * 32, r0 = blockIdx.y * 32;   // s: token, r: channel
    int tx = threadIdx.x & 31, ty = threadIdx.x >> 5;
#pragma unroll
    for (int i = 0; i < 4; i++)
        tile[ty + i * 8][tx] = inb[(size_t)(r0 + ty + i * 8) * NTOK + s0 + tx];
    __syncthreads();
    int rq = threadIdx.x & 7, sy = threadIdx.x >> 3;  // rq: channel quad, sy: token
    ushort4 o;
    o.x = f2h(tile[rq * 4 + 0][sy]);
    o.y = f2h(tile[rq * 4 + 1][sy]);
    o.z = f2h(tile[rq * 4 + 2][sy]);
    o.w = f2h(tile[rq * 4 + 3][sy]);
    *reinterpret_cast<ushort4*>(outb + (size_t)(s0 + sy) * 512 + r0 + rq * 4) = o;
}

// ---------------------------------------------------------------------------
// Weight converts. z: 0 Wq(blocked) 1 Wo1(blocked) 2 Wout(FLAT N^T x K,
// staged to LDS by out-GEMM) 3 Wo2(blocked) 4 Wa(blocked). Pad rows zeroed.
// ---------------------------------------------------------------------------
__global__ __launch_bounds__(256) void wcvt_all(
    const float* __restrict__ W0, u16* __restrict__ T0,
    const float* __restrict__ W1, u16* __restrict__ T1,
    const float* __restrict__ W2, u16* __restrict__ T2,
    const float* __restrict__ W3, u16* __restrict__ T3,
    const float* __restrict__ W4, u16* __restrict__ T4)
{
    const float* W; u16* Wt; int Nout, Npad;
    switch (blockIdx.z) {
        case 0: W = W0; Wt = T0; Nout = 512; Npad = 512; break;
        case 1: W = W1; Wt = T1; Nout = 512; Npad = 512; break;
        case 2: W = W2; Wt = T2; Nout = 512; Npad = 512; break;
        case 3: W = W3; Wt = T3; Nout = 96;  Npad = 128; break;
        default: W = W4; Wt = T4; Nout = 32; Npad = 128; break;
    }
    int blocked = (blockIdx.z != 2);
    int n0 = blockIdx.x * 32, k0 = blockIdx.y * 32;
    if (n0 >= Npad) return;
    __shared__ float t[32][33];
    int tx = threadIdx.x & 31, ty = threadIdx.x >> 5;
#pragma unroll
    for (int i = 0; i < 4; i++) {
        int k = k0 + ty + i * 8, n = n0 + tx;
        t[ty + i * 8][tx] = (n < Nout) ? W[(size_t)k * Nout + n] : 0.f;
    }
    __syncthreads();
#pragma unroll
    for (int i = 0; i < 4; i++) {
        int n = n0 + ty + i * 8, k = k0 + tx;
        u16 v = f2h(t[tx][ty + i * 8]);
        if (blocked) Wt[bidx(n, k)] = v;
        else         Wt[(size_t)n * 512 + k] = v;
    }
}

// ---------------------------------------------------------------------------
// R16: fused MLP, re-geared for occupancy. R15 post-mortem: 64-token blocks
// (137.7KB LDS) -> 1 block/CU -> 2 waves/SIMD (Occ 19.5%) + 2.36M LDS bank
// conflicts from scalar u16 LN stores (1040B/lane stride = 8-way). Now:
// 32-token blocks x 500, ~70KB LDS -> 2 blocks/CU -> 4 waves/SIMD. Each
// wave owns ALL 32 tokens x 64 cols (2 A-frags, 4 B-frags, 8 MFMA per kk)
// -> block reads each weight matrix exactly once (no intra-block redundant
// B traffic). LN-apply writes f16x8 chunks (b128): a 520-u16 row = 65
// granules (odd) -> column b128 access is conflict-free by construction.
// B-ring 3-deep (8 in flight, VMWAIT(8/4/0)) keeps VGPR < 128 at 4 w/SIMD.
// ---------------------------------------------------------------------------
__device__ __forceinline__ void lds_gemm32(
    const u16* Tin, u16* Tout, const u16* __restrict__ Wblk,
    const float* __restrict__ bias, int relu, int lane, int wv)
{
    int ml = lane & 15, quad = lane >> 4;
    int c0 = wv * 64;                       // wave's 64-col slice
    const u16* Bp = Wblk + (size_t)(c0 >> 4) * 8192 + (size_t)lane * 8;
    const u16* Ar0 = Tin + ml * 520;        // tokens 0..15
    const u16* Ar1 = Tin + (16 + ml) * 520; // tokens 16..31

    f32x4 acc[2][4];
#pragma unroll
    for (int t = 0; t < 2; t++)
#pragma unroll
        for (int j = 0; j < 4; j++) acc[t][j] = (f32x4){0.f, 0.f, 0.f, 0.f};

    f32x4 bfr[3][4];   // ring [batch%3][j], 2 batches ahead
#pragma unroll
    for (int kb = 0; kb < 2; kb++)
#pragma unroll
        for (int j = 0; j < 4; j++)
            bfr[kb][j] = agload16(Bp + (size_t)j * 8192 + kb * 512);

#pragma unroll
    for (int kk = 0; kk < 16; kk++) {
        if (kk + 2 < 16) {
#pragma unroll
            for (int j = 0; j < 4; j++)
                bfr[(kk + 2) % 3][j] = agload16(
                    Bp + (size_t)j * 8192 + (kk + 2) * 512);
        }
        f16x8 a0 = *reinterpret_cast<const f16x8*>(Ar0 + (kk * 4 + quad) * 8);
        f16x8 a1 = *reinterpret_cast<const f16x8*>(Ar1 + (kk * 4 + quad) * 8);
        if (kk < 14)       VMWAIT(8);
        else if (kk == 14) VMWAIT(4);
        else               VMWAIT(0);
#pragma unroll
        for (int j = 0; j < 4; j++) {
            f16x8 bj = __builtin_bit_cast(f16x8, bfr[kk % 3][j]);
            acc[0][j] = __builtin_amdgcn_mfma_f32_16x16x32_f16(
                a0, bj, acc[0][j], 0, 0, 0);
            acc[1][j] = __builtin_amdgcn_mfma_f32_16x16x32_f16(
                a1, bj, acc[1][j], 0, 0, 0);
        }
    }

    // C/D: col=lane&15, row=quad*4+reg (m89/m91)
#pragma unroll
    for (int t = 0; t < 2; t++)
#pragma unroll
        for (int j = 0; j < 4; j++) {
            int col = c0 + j * 16 + ml;
            float bia = bias[col];
#pragma unroll
            for (int rg = 0; rg < 4; rg++) {
                float v = acc[t][j][rg] + bia;
                if (relu) v = fmaxf(v, 0.f);
                Tout[(t * 16 + quad * 4 + rg) * 520 + col] = f2h(v);
            }
        }
}

__global__ __launch_bounds__(512, 4) void mlp_fused(
    const float* __restrict__ fq, const float* __restrict__ gamma,
    const float* __restrict__ beta,
    const u16* __restrict__ Wqb, const float* __restrict__ bq,
    const u16* __restrict__ Wo1b, const float* __restrict__ bo1,
    const u16* __restrict__ Wo2b, const float* __restrict__ bo2,
    const u16* __restrict__ Wab, const float* __restrict__ ba,
    float* __restrict__ offb, float* __restrict__ lgb)
{
    __shared__ u16 T0[32 * 520], T1[32 * 520];     // 66.6 KB
    __shared__ float ps[32][17], pq[32][17];       // 17-pad: odd stride
    __shared__ float muA[32], rsA[32];
    int tid = threadIdx.x, lane = tid & 63, wv = tid >> 6;
    int blk = blockIdx.x;                // 500 blocks; 250 per batch (exact)
    int tp = tid & 31;                   // token in tile
    int cg = tid >> 5;                   // 0..15 chunk-group
    int b = blk >= 250;
    int n0 = (blk - b * 250) * 32;
    const float* src = fq + (size_t)b * C_DIM * NTOK + n0 + tp;

    // ---- LN stats: thread (tp, cg) sums chunks {cg, cg+16, cg+32, cg+48} --
    {
        float s = 0.f, q = 0.f;
#pragma unroll
        for (int it = 0; it < 4; ++it) {
            int c0 = (cg + it * 16) * 8;
#pragma unroll
            for (int e = 0; e < 8; ++e) {
                float v = src[(size_t)(c0 + e) * NTOK];
                s += v; q += v * v;
            }
        }
        ps[tp][cg] = s; pq[tp][cg] = q;
    }
    __syncthreads();
    if (tid < 32) {
        float S = 0.f, SQ = 0.f;
#pragma unroll
        for (int g = 0; g < 16; ++g) { S += ps[tid][g]; SQ += pq[tid][g]; }
        float mu = S * (1.f / 512.f);
        muA[tid] = mu;
        rsA[tid] = rsqrtf(SQ * (1.f / 512.f) - mu * mu + 1e-5f);
    }
    __syncthreads();
    // ---- LN apply: re-read (L2-warm), pack 8ch -> one b128 LDS store ----
    {
        float mu = muA[tp], rs = rsA[tp];
#pragma unroll
        for (int it = 0; it < 4; ++it) {
            int c0 = (cg + it * 16) * 8;
            u16 o[8];
#pragma unroll
            for (int e = 0; e < 8; ++e) {
                float v = src[(size_t)(c0 + e) * NTOK];
                o[e] = f2h((v - mu) * rs * gamma[c0 + e] + beta[c0 + e]);
            }
            *reinterpret_cast<f16x8*>(&T0[tp * 520 + c0]) =
                *reinterpret_cast<const f16x8*>(o);
        }
    }
    __syncthreads();
    // ---- Q = q @ Wq + bq : T0 -> T1 ----
    lds_gemm32(T0, T1, Wqb, bq, 0, lane, wv);
    __syncthreads();
    // ---- hid = relu(Q @ Wo1 + bo1) : T1 -> T0 ----
    lds_gemm32(T1, T0, Wo1b, bo1, 1, lane, wv);
    __syncthreads();
    // ---- off (waves 0-5: hid@Wo2, 96 cols) & logits (waves 6-7: Q@Wa) ----
    {
        int ml = lane & 15, quad = lane >> 4;
        int isLg = wv >= 6;
        int cb = isLg ? (wv - 6) : wv;             // 16-col block
        const u16* Tin = isLg ? T1 : T0;
        const u16* Wsm = isLg ? Wab : Wo2b;
        const float* bs = isLg ? ba : bo2;
        float* outg = isLg ? lgb : offb;
        int ldo = isLg ? 32 : 96;
        // preload wave's full 16-col x 512-K weight panel to registers
        const u16* Wp = Wsm + (size_t)cb * 8192 + (size_t)lane * 8;
        f16x8 wb[16];
#pragma unroll
        for (int kk = 0; kk < 16; kk++)
            wb[kk] = *reinterpret_cast<const f16x8*>(Wp + (size_t)kk * 512);
        float bia = bs[cb * 16 + ml];
        int tbase = blk * 32;
#pragma unroll
        for (int tg = 0; tg < 2; tg++) {
            f32x4 acc = (f32x4){0.f, 0.f, 0.f, 0.f};
            const u16* Ar = Tin + (tg * 16 + ml) * 520;
#pragma unroll
            for (int kk = 0; kk < 16; kk++) {
                f16x8 af = *reinterpret_cast<const f16x8*>(
                    Ar + (kk * 4 + quad) * 8);
                acc = __builtin_amdgcn_mfma_f32_16x16x32_f16(
                    af, wb[kk], acc, 0, 0, 0);
            }
#pragma unroll
            for (int rg = 0; rg < 4; rg++)
                outg[(size_t)(tbase + tg * 16 + quad * 4 + rg) * ldo
                     + cb * 16 + ml] = acc[rg] + bia;
        }
    }
}

// ---------------------------------------------------------------------------
// Weight-stationary out-GEMM (R14, unchanged): blocked-A coalesced frag
// loads + asm ring + counted vmcnt; 64KB resident flat Wout panel.
// fp32 transposed (B,C,N) store: [(b*512+col)*8000 + tok], float4.
// ---------------------------------------------------------------------------
__device__ __forceinline__ void ws_body512(
    const u16* __restrict__ A, const u16* __restrict__ Bp,
    const float* __restrict__ bias, float* __restrict__ Cf,
    int colBase, int mt)
{
    __shared__ u16 Bs[64 * 512];   // 64 KB
    int tid = threadIdx.x, lane = tid & 63, wv = tid >> 6;   // wv 0..7

#pragma unroll
    for (int c = 0; c < 8; c++) {
        int id = c * 512 + tid;
        int row = id >> 6, seg = id & 63;
        async16(Bp + (size_t)row * 512 + ((seg ^ (row & 7)) << 3),
                Bs + (size_t)id * 8);
    }

    int ml = lane & 15, quad = lane >> 4;
    int wm = (wv >> 1) * 64, wn = (wv & 1) * 32;   // 4x2 wave grid, 256x64

    int rowj[2];
#pragma unroll
    for (int j = 0; j < 2; j++) rowj[j] = wn + j * 16 + ml;

    __syncthreads();   // panel resident; vmcnt drained -> counts start clean

    int bm = mt * 256;
    const u16* Ap = A + ((size_t)((bm + wm) >> 4)) * 8192 + (size_t)lane * 8;

    f32x4 acc[4][2];
#pragma unroll
    for (int i = 0; i < 4; i++)
#pragma unroll
        for (int j = 0; j < 2; j++) acc[i][j] = (f32x4){0.f, 0.f, 0.f, 0.f};

    f32x4 afr[4][4];
    f16x8 bf[2][2];

#pragma unroll
    for (int kb = 0; kb < 3; kb++)
#pragma unroll
        for (int i = 0; i < 4; i++)
            afr[kb][i] = agload16(Ap + (size_t)i * 8192 + kb * 512);
#pragma unroll
    for (int j = 0; j < 2; j++)
        bf[0][j] = *reinterpret_cast<const f16x8*>(
            Bs + (size_t)rowj[j] * 512 + (((0 + quad) ^ (rowj[j] & 7)) << 3));

#pragma unroll
    for (int kk = 0; kk < 16; kk++) {
        if (kk + 3 < 16) {
#pragma unroll
            for (int i = 0; i < 4; i++)
                afr[(kk + 3) & 3][i] = agload16(
                    Ap + (size_t)i * 8192 + (kk + 3) * 512);
        }
        if (kk + 1 < 16) {
#pragma unroll
            for (int j = 0; j < 2; j++) {
                int seg = (kk + 1) * 4 + quad;
                bf[(kk + 1) & 1][j] = *reinterpret_cast<const f16x8*>(
                    Bs + (size_t)rowj[j] * 512 + ((seg ^ (rowj[j] & 7)) << 3));
            }
        }
        if (kk < 13)       VMWAIT(12);
        else if (kk == 13) VMWAIT(8);
        else if (kk == 14) VMWAIT(4);
        else               VMWAIT(0);
#pragma unroll
        for (int i = 0; i < 4; i++)
#pragma unroll
            for (int j = 0; j < 2; j++)
                acc[i][j] = __builtin_amdgcn_mfma_f32_16x16x32_f16(
                    __builtin_bit_cast(f16x8, afr[kk & 3][i]),
                    bf[kk & 1][j], acc[i][j], 0, 0, 0);
    }

#pragma unroll
    for (int i = 0; i < 4; i++) {
        int row = bm + wm + i * 16 + quad * 4;   // token index (4 consec)
        if (row >= BN_TOK) continue;             // tail tile guard
#pragma unroll
        for (int j = 0; j < 2; j++) {
            int col = colBase + wn + j * 16 + ml;
            float bia = bias[col];
            int bb = row >= 8000;
            float4 st;
            st.x = acc[i][j][0] + bia;
            st.y = acc[i][j][1] + bia;
            st.z = acc[i][j][2] + bia;
            st.w = acc[i][j][3] + bia;
            *reinterpret_cast<float4*>(
                Cf + ((size_t)(bb * 512 + col)) * 8000 + (row - bb * 8000)) = st;
        }
    }
}

// 512 flat blocks = 8 panels x 64 M-groups; same-XCD decode for A-reuse.
__global__ __launch_bounds__(512, 4) void gemm_out(
    const u16* __restrict__ A, const u16* __restrict__ WT,
    const float* __restrict__ bias, float* __restrict__ Cf)
{
    int did = blockIdx.x;                      // 0..511
    int m = ((did >> 6) << 3) | (did & 7);     // M-group 0..63
    if (m >= 63) return;                       // 63 tiles of 256 cover 16000
    int p = (did >> 3) & 7;                    // panel 0..7
    ws_body512(A, WT + (size_t)p * 64 * 512, bias, Cf, p * 64, m);
}

// ---------------------------------------------------------------------------
// Fused softmax + offset clip + trilinear sample + einsum, f16 volume.
// Output (sampled) stored in BLOCKED layout (consumed as A by out-GEMM).
// ---------------------------------------------------------------------------
__global__ __launch_bounds__(256) void sample_kernel(
    const u16* __restrict__ vol, const float* __restrict__ offb,
    const float* __restrict__ lgb, u16* __restrict__ outp)
{
    int wid = threadIdx.x >> 6, lane = threadIdx.x & 63;
    int bx = blockIdx.x;                               // 4000 = 8 slabs x 500
    int bn = ((bx & 7) * 500 + (bx >> 3)) * 4 + wid;   // token 0..15999
    int h = lane >> 3, cl = lane & 7;
    int b = bn / NTOK, n = bn - b * NTOK;
    int y = n / 400;
    int r2 = n - y * 400;
    int x = r2 / 20;
    int z = r2 - x * 20;

    const float* op = offb + (size_t)bn * 96 + h * 12;
    const float* lp = lgb + (size_t)bn * 32 + h * 4;
    float l0 = lp[0], l1 = lp[1], l2 = lp[2], l3 = lp[3];
    float mx = fmaxf(fmaxf(l0, l1), fmaxf(l2, l3));
    float e0 = expf(l0 - mx), e1 = expf(l1 - mx), e2 = expf(l2 - mx), e3 = expf(l3 - mx);
    float inv = 1.f / (e0 + e1 + e2 + e3);
    float at[4] = {e0 * inv, e1 * inv, e2 * inv, e3 * inv};

    const u16* volb = vol + b * (NTOK * C_DIM) + h * HDIM + cl * 8;
    h2 acc0 = (h2)(_Float16)0, acc1 = acc0, acc2 = acc0, acc3 = acc0;
#pragma unroll 1
    for (int p = 0; p < 4; p++) {
        float o0 = fminf(fmaxf(op[p * 3 + 0], -3.f), 3.f);
        float o1 = fminf(fmaxf(op[p * 3 + 1], -3.f), 3.f);
        float o2 = fminf(fmaxf(op[p * 3 + 2], -3.f), 3.f);
        float ix = fminf(fmaxf((float)y + o0, 0.f), 19.f);  // W axis
        float iy = fminf(fmaxf((float)x + o1, 0.f), 19.f);  // H axis
        float iz = fminf(fmaxf((float)z + o2, 0.f), 19.f);  // D axis
        float xf = floorf(ix), yf = floorf(iy), zf = floorf(iz);
        float fx = ix - xf, fy = iy - yf, fz = iz - zf;
        int x0 = (int)xf, y0 = (int)yf, z0 = (int)zf;
        int x1 = imin(x0 + 1, 19), y1 = imin(y0 + 1, 19), z1 = imin(z0 + 1, 19);
        int s00 = y0 * 400 + x0 * 20, s01 = y0 * 400 + x1 * 20;
        int s10 = y1 * 400 + x0 * 20, s11 = y1 * 400 + x1 * 20;
        uint4 v000 = *(const uint4*)(volb + (s00 + z0) * C_DIM);
        uint4 v001 = *(const uint4*)(volb + (s01 + z0) * C_DIM);
        uint4 v010 = *(const uint4*)(volb + (s10 + z0) * C_DIM);
        uint4 v011 = *(const uint4*)(volb + (s11 + z0) * C_DIM);
        uint4 v100 = *(const uint4*)(volb + (s00 + z1) * C_DIM);
        uint4 v101 = *(const uint4*)(volb + (s01 + z1) * C_DIM);
        uint4 v110 = *(const uint4*)(volb + (s10 + z1) * C_DIM);
        uint4 v111 = *(const uint4*)(volb + (s11 + z1) * C_DIM);
        float wz0 = (1.f - fz) * at[p], wz1 = fz * at[p];
        float w00 = wz0 * (1.f - fy), w01 = wz0 * fy;
        float w10 = wz1 * (1.f - fy), w11 = wz1 * fy;
        float gx0 = 1.f - fx;
        float cw[8] = { w00 * gx0, w00 * fx, w01 * gx0, w01 * fx,
                        w10 * gx0, w10 * fx, w11 * gx0, w11 * fx };
        const uint4* cv[8] = { &v000, &v001, &v010, &v011,
                               &v100, &v101, &v110, &v111 };
#pragma unroll
        for (int c = 0; c < 8; c++) {
            _Float16 wh = (_Float16)cw[c];
            h2 w2; w2.x = wh; w2.y = wh;
            uint4 d = *cv[c];
            acc0 += __builtin_bit_cast(h2, d.x) * w2;
            acc1 += __builtin_bit_cast(h2, d.y) * w2;
            acc2 += __builtin_bit_cast(h2, d.z) * w2;
            acc3 += __builtin_bit_cast(h2, d.w) * w2;
        }
    }
    uint4 o;
    o.x = __builtin_bit_cast(unsigned, acc0);
    o.y = __builtin_bit_cast(unsigned, acc1);
    o.z = __builtin_bit_cast(unsigned, acc2);
    o.w = __builtin_bit_cast(unsigned, acc3);
    *reinterpret_cast<uint4*>(outp + aidx(bn, h * HDIM + cl * 8)) = o;
}

// ---------------------------------------------------------------------------
// Launch
// ---------------------------------------------------------------------------
extern "C" void kernel_launch(void* const* d_in, const int* in_sizes, int n_in,
                              void* d_out, int out_size, void* d_ws, size_t ws_size,
                              hipStream_t stream)
{
    const float* f_query = (const float*)d_in[0];
    const float* f_kv    = (const float*)d_in[1];
    const float* ln_g    = (const float*)d_in[2];
    const float* ln_b    = (const float*)d_in[3];
    const float* Wq      = (const float*)d_in[4];
    const float* bq      = (const float*)d_in[5];
    const float* Wo1     = (const float*)d_in[6];
    const float* bo1     = (const float*)d_in[7];
    const float* Wo2     = (const float*)d_in[8];
    const float* bo2     = (const float*)d_in[9];
    const float* Wa      = (const float*)d_in[10];
    const float* ba      = (const float*)d_in[11];
    const float* Wout    = (const float*)d_in[12];
    const float* bout    = (const float*)d_in[13];
    float* out = (float*)d_out;

    float* ws = (float*)d_ws;
    float* offb = ws;                     // 1,536,000 f
    float* lgb  = ws + 1536000;           //   512,000 f
    u16* kvT   = (u16*)(ws + 2048000);    // 16000x512 (f16 channels-last)
    u16* qb    = kvT  + 8192000;          // 16000x512 (blocked: sampled out)
    u16* WqT   = qb   + 8192000;          // 512x512 blocked
    u16* Wo1T  = WqT + 262144;            // 512x512 blocked
    u16* WoutT = Wo1T + 262144;           // 512x512 flat
    u16* Wo2T  = WoutT + 262144;          // 128x512 blocked (96 valid)
    u16* WaT   = Wo2T + 65536;            // 128x512 blocked (32 valid)

    dim3 blk(256);
    dim3 blk512(512);
    // weight converts (blocked for mlp; flat for Wout)
    wcvt_all<<<dim3(16, 16, 5), blk, 0, stream>>>(
        Wq, WqT, Wo1, Wo1T, Wout, WoutT, Wo2, Wo2T, Wa, WaT);
    // f_kv (B,C,N) fp32 -> kvT (B,N,C) f16
    transpose_c2l_f16<<<dim3(250, 16, 2), blk, 0, stream>>>(f_kv, kvT);
    // fused LN -> Q -> hid -> off/logits (token-local chain, one dispatch)
    mlp_fused<<<dim3(500), blk512, 0, stream>>>(
        f_query, ln_g, ln_b, WqT, bq, Wo1T, bo1, Wo2T, bo2, WaT, ba,
        offb, lgb);
    // fused sample/softmax/einsum -> qb (f16 blocked)
    sample_kernel<<<dim3(4000), blk, 0, stream>>>(kvT, offb, lgb, qb);
    // out(B,C,N) = (sampled @ Wout + bout)^T
    gemm_out<<<dim3(512), blk512, 0, stream>>>(qb, WoutT, bout, out);
}

// Round 10
// 195.626 us; speedup vs baseline: 1.4585x; 1.0367x over previous
//
#include <hip/hip_runtime.h>
#include <math.h>

// Problem constants
#define C_DIM 512
#define NHEAD 8
#define HDIM 64
#define NTOK 8000
#define BN_TOK 16000

typedef __attribute__((ext_vector_type(8))) _Float16 f16x8;
typedef __attribute__((ext_vector_type(4))) float f32x4;
typedef __attribute__((ext_vector_type(2))) _Float16 h2;
typedef unsigned short u16;

__device__ __forceinline__ int imin(int a, int b) { return a < b ? a : b; }

// fp32 -> f16 (RNE)
__device__ __forceinline__ u16 f2h(float x) {
    _Float16 h = (_Float16)x;
    return __builtin_bit_cast(u16, h);
}

// MFMA-fragment-major blocked layout (R14, proven): token-major matrices.
// u16 index for (token t, channel c): block 16 tok x 512 ch = 8192 u16;
// a wave's 16x16x32 A-frag = base + lane*8 u16 -> one coalesced 1KB dwordx4.
__device__ __forceinline__ size_t aidx(int t, int c) {
    return ((size_t)(t >> 4)) * 8192 + (size_t)((c >> 5) * 512
         + (((c >> 3) & 3) * 128) + ((t & 15) * 8) + (c & 7));
}
// Same layout for weights as B-operand: (out-col n, k). Wave's B-frag for
// col-block cb, k-step kk = Wblk + cb*8192 + kk*512 + lane*8 (coalesced 1KB).
__device__ __forceinline__ size_t bidx(int n, int k) {
    return ((size_t)(n >> 4)) * 8192 + (size_t)((k >> 5) * 512
         + (((k >> 3) & 3) * 128) + ((n & 15) * 8) + (k & 7));
}

// async global->LDS, 16 bytes per lane (global_load_lds_dwordx4)
__device__ __forceinline__ void async16(const void* g, void* l) {
    __builtin_amdgcn_global_load_lds(
        (const __attribute__((address_space(1))) void*)g,
        (__attribute__((address_space(3))) void*)l, 16, 0, 0);
}

// compiler-proof 16B global load (asm volatile: un-sinkable, issue-ordered)
__device__ __forceinline__ f32x4 agload16(const u16* p) {
    f32x4 r;
    asm volatile("global_load_dwordx4 %0, %1, off" : "=v"(r) : "v"(p));
    return r;
}

// counted vmcnt + scheduler fence (rule #18). Extra compiler loads issued
// earlier only make the wait stricter (vmcnt drains in issue order) -> safe.
#define VMWAIT(N) do { asm volatile("s_waitcnt vmcnt(" #N ")"); \
                       __builtin_amdgcn_sched_barrier(0); } while (0)

// ---------------------------------------------------------------------------
// f_kv (B,C,N) fp32 -> kvT (B,N,C) f16. Fixed 512 x 8000 per batch.
// (kvT stays channels-contiguous row-major: consumed by sample gather.)
// ---------------------------------------------------------------------------
__global__ __launch_bounds__(256) void transpose_c2l_f16(
    const float* __restrict__ in, u16* __restrict__ out)
{
    __shared__ float tile[32][33];
    int b = blockIdx.z;
    const float* inb = in + (size_t)b * 512 * NTOK;
    u16* outb = out + (size_t)b * NTOK * 512;
    int s0 = blockIdx.x * 32, r0 = blockIdx.y * 32;   // s: token, r: channel
    int tx = threadIdx.x & 31, ty = threadIdx.x >> 5;
#pragma unroll
    for (int i = 0; i < 4; i++)
        tile[ty + i * 8][tx] = inb[(size_t)(r0 + ty + i * 8) * NTOK + s0 + tx];
    __syncthreads();
    int rq = threadIdx.x & 7, sy = threadIdx.x >> 3;  // rq: channel quad, sy: token
    ushort4 o;
    o.x = f2h(tile[rq * 4 + 0][sy]);
    o.y = f2h(tile[rq * 4 + 1][sy]);
    o.z = f2h(tile[rq * 4 + 2][sy]);
    o.w = f2h(tile[rq * 4 + 3][sy]);
    *reinterpret_cast<ushort4*>(outb + (size_t)(s0 + sy) * 512 + r0 + rq * 4) = o;
}

// ---------------------------------------------------------------------------
// Weight converts. z: 0 Wq(blocked) 1 Wo1(blocked) 2 Wout(FLAT N^T x K,
// staged to LDS by out-GEMM) 3 Wo2(blocked) 4 Wa(blocked). Pad rows zeroed.
// ---------------------------------------------------------------------------
__global__ __launch_bounds__(256) void wcvt_all(
    const float* __restrict__ W0, u16* __restrict__ T0,
    const float* __restrict__ W1, u16* __restrict__ T1,
    const float* __restrict__ W2, u16* __restrict__ T2,
    const float* __restrict__ W3, u16* __restrict__ T3,
    const float* __restrict__ W4, u16* __restrict__ T4)
{
    const float* W; u16* Wt; int Nout, Npad;
    switch (blockIdx.z) {
        case 0: W = W0; Wt = T0; Nout = 512; Npad = 512; break;
        case 1: W = W1; Wt = T1; Nout = 512; Npad = 512; break;
        case 2: W = W2; Wt = T2; Nout = 512; Npad = 512; break;
        case 3: W = W3; Wt = T3; Nout = 96;  Npad = 128; break;
        default: W = W4; Wt = T4; Nout = 32; Npad = 128; break;
    }
    int blocked = (blockIdx.z != 2);
    int n0 = blockIdx.x * 32, k0 = blockIdx.y * 32;
    if (n0 >= Npad) return;
    __shared__ float t[32][33];
    int tx = threadIdx.x & 31, ty = threadIdx.x >> 5;
#pragma unroll
    for (int i = 0; i < 4; i++) {
        int k = k0 + ty + i * 8, n = n0 + tx;
        t[ty + i * 8][tx] = (n < Nout) ? W[(size_t)k * Nout + n] : 0.f;
    }
    __syncthreads();
#pragma unroll
    for (int i = 0; i < 4; i++) {
        int n = n0 + ty + i * 8, k = k0 + tx;
        u16 v = f2h(t[tx][ty + i * 8]);
        if (blocked) Wt[bidx(n, k)] = v;
        else         Wt[(size_t)n * 512 + k] = v;
    }
}

// ---------------------------------------------------------------------------
// R18 = R17 resubmitted (R9 bench was an infrastructure failure, no signal).
// Fused MLP, weight-traffic-minimal geometry. R16 post-mortem: 500 blocks
// each streaming the full 1.15MB weight set -> 2.3MB per CU through the
// ~56B/cyc L2 port = 17.5us floor; 4 waves/SIMD x 19cyc MFMA per 4-load
// batch couldn't cover ~300cyc L2 latency (MfmaUtil 17%). Now: 64-token
// blocks x 250, 8 waves, wave owns 64 cols x ALL 64 tokens -> per kk:
// 4 B loads + 4 A ds_reads + 16 MFMA (~77cyc). Block reads each weight
// matrix ONCE: 1.15MB/CU (8.5us floor, halved) and 4x the per-batch
// compute cover of R15's 2-wave/SIMD regime. LDS T0+T1 = 133KB -> 1
// block/CU (deliberate occupancy-for-traffic trade). launch_bounds(512,2)
// -> 256 VGPR budget, acc[4][4]+ring ~150 VGPR, no spill.
// ---------------------------------------------------------------------------
__device__ __forceinline__ void lds_gemm64(
    const u16* Tin, u16* Tout, const u16* __restrict__ Wblk,
    const float* __restrict__ bias, int relu, int lane, int wv)
{
    int ml = lane & 15, quad = lane >> 4;
    int c0 = wv * 64;                       // wave's 64-col slice
    const u16* Bp = Wblk + (size_t)(c0 >> 4) * 8192 + (size_t)lane * 8;

    f32x4 acc[4][4];
#pragma unroll
    for (int t = 0; t < 4; t++)
#pragma unroll
        for (int j = 0; j < 4; j++) acc[t][j] = (f32x4){0.f, 0.f, 0.f, 0.f};

    f32x4 bfr[3][4];   // ring [batch%3][j], 2 batches ahead
#pragma unroll
    for (int kb = 0; kb < 2; kb++)
#pragma unroll
        for (int j = 0; j < 4; j++)
            bfr[kb][j] = agload16(Bp + (size_t)j * 8192 + kb * 512);

#pragma unroll
    for (int kk = 0; kk < 16; kk++) {
        if (kk + 2 < 16) {
#pragma unroll
            for (int j = 0; j < 4; j++)
                bfr[(kk + 2) % 3][j] = agload16(
                    Bp + (size_t)j * 8192 + (kk + 2) * 512);
        }
        f16x8 a[4];
#pragma unroll
        for (int t = 0; t < 4; t++)
            a[t] = *reinterpret_cast<const f16x8*>(
                Tin + (t * 16 + ml) * 520 + (kk * 4 + quad) * 8);
        if (kk < 14)       VMWAIT(8);
        else if (kk == 14) VMWAIT(4);
        else               VMWAIT(0);
#pragma unroll
        for (int j = 0; j < 4; j++) {
            f16x8 bj = __builtin_bit_cast(f16x8, bfr[kk % 3][j]);
#pragma unroll
            for (int t = 0; t < 4; t++)
                acc[t][j] = __builtin_amdgcn_mfma_f32_16x16x32_f16(
                    a[t], bj, acc[t][j], 0, 0, 0);
        }
    }

    // C/D: col=lane&15, row=quad*4+reg (m89/m91)
#pragma unroll
    for (int t = 0; t < 4; t++)
#pragma unroll
        for (int j = 0; j < 4; j++) {
            int col = c0 + j * 16 + ml;
            float bia = bias[col];
#pragma unroll
            for (int rg = 0; rg < 4; rg++) {
                float v = acc[t][j][rg] + bia;
                if (relu) v = fmaxf(v, 0.f);
                Tout[(t * 16 + quad * 4 + rg) * 520 + col] = f2h(v);
            }
        }
}

__global__ __launch_bounds__(512, 2) void mlp_fused(
    const float* __restrict__ fq, const float* __restrict__ gamma,
    const float* __restrict__ beta,
    const u16* __restrict__ Wqb, const float* __restrict__ bq,
    const u16* __restrict__ Wo1b, const float* __restrict__ bo1,
    const u16* __restrict__ Wo2b, const float* __restrict__ bo2,
    const u16* __restrict__ Wab, const float* __restrict__ ba,
    float* __restrict__ offb, float* __restrict__ lgb)
{
    __shared__ u16 T0[64 * 520], T1[64 * 520];     // 133.1 KB
    __shared__ float ps[64][9], pq[64][9];
    __shared__ float muA[64], rsA[64];
    int tid = threadIdx.x, lane = tid & 63, wv = tid >> 6;
    int blk = blockIdx.x;                // 250 blocks; 125 per batch (exact)
    int tp = tid & 63;                   // token in tile
    int cg = tid >> 6;                   // 0..7 chunk-group
    int b = blk >= 125;
    int n0 = (blk - b * 125) * 64;
    const float* src = fq + (size_t)b * C_DIM * NTOK + n0 + tp;

    // ---- LN stats: thread (tp, cg) sums chunks {cg, cg+8, ..., cg+56} ----
    {
        float s = 0.f, q = 0.f;
#pragma unroll
        for (int it = 0; it < 8; ++it) {
            int c0 = (cg + it * 8) * 8;
#pragma unroll
            for (int e = 0; e < 8; ++e) {
                float v = src[(size_t)(c0 + e) * NTOK];
                s += v; q += v * v;
            }
        }
        ps[tp][cg] = s; pq[tp][cg] = q;
    }
    __syncthreads();
    if (tid < 64) {
        float S = 0.f, SQ = 0.f;
#pragma unroll
        for (int g = 0; g < 8; ++g) { S += ps[tid][g]; SQ += pq[tid][g]; }
        float mu = S * (1.f / 512.f);
        muA[tid] = mu;
        rsA[tid] = rsqrtf(SQ * (1.f / 512.f) - mu * mu + 1e-5f);
    }
    __syncthreads();
    // ---- LN apply: re-read (L2-warm), pack 8ch -> one b128 LDS store ----
    {
        float mu = muA[tp], rs = rsA[tp];
#pragma unroll
        for (int it = 0; it < 8; ++it) {
            int c0 = (cg + it * 8) * 8;
            u16 o[8];
#pragma unroll
            for (int e = 0; e < 8; ++e) {
                float v = src[(size_t)(c0 + e) * NTOK];
                o[e] = f2h((v - mu) * rs * gamma[c0 + e] + beta[c0 + e]);
            }
            *reinterpret_cast<f16x8*>(&T0[tp * 520 + c0]) =
                *reinterpret_cast<const f16x8*>(o);
        }
    }
    __syncthreads();
    // ---- Q = q @ Wq + bq : T0 -> T1 ----
    lds_gemm64(T0, T1, Wqb, bq, 0, lane, wv);
    __syncthreads();
    // ---- hid = relu(Q @ Wo1 + bo1) : T1 -> T0 ----
    lds_gemm64(T1, T0, Wo1b, bo1, 1, lane, wv);
    __syncthreads();
    // ---- off (waves 0-5: hid@Wo2, 96 cols) & logits (waves 6-7: Q@Wa) ----
    {
        int ml = lane & 15, quad = lane >> 4;
        int isLg = wv >= 6;
        int cb = isLg ? (wv - 6) : wv;             // 16-col block
        const u16* Tin = isLg ? T1 : T0;
        const u16* Wsm = isLg ? Wab : Wo2b;
        const float* bs = isLg ? ba : bo2;
        float* outg = isLg ? lgb : offb;
        int ldo = isLg ? 32 : 96;
        // preload wave's full 16-col x 512-K weight panel to registers
        const u16* Wp = Wsm + (size_t)cb * 8192 + (size_t)lane * 8;
        f16x8 wb[16];
#pragma unroll
        for (int kk = 0; kk < 16; kk++)
            wb[kk] = *reinterpret_cast<const f16x8*>(Wp + (size_t)kk * 512);
        float bia = bs[cb * 16 + ml];
        int tbase = blk * 64;
#pragma unroll
        for (int tg = 0; tg < 4; tg++) {
            f32x4 acc = (f32x4){0.f, 0.f, 0.f, 0.f};
            const u16* Ar = Tin + (tg * 16 + ml) * 520;
#pragma unroll
            for (int kk = 0; kk < 16; kk++) {
                f16x8 af = *reinterpret_cast<const f16x8*>(
                    Ar + (kk * 4 + quad) * 8);
                acc = __builtin_amdgcn_mfma_f32_16x16x32_f16(
                    af, wb[kk], acc, 0, 0, 0);
            }
#pragma unroll
            for (int rg = 0; rg < 4; rg++)
                outg[(size_t)(tbase + tg * 16 + quad * 4 + rg) * ldo
                     + cb * 16 + ml] = acc[rg] + bia;
        }
    }
}

// ---------------------------------------------------------------------------
// Weight-stationary out-GEMM (R14, unchanged): blocked-A coalesced frag
// loads + asm ring + counted vmcnt; 64KB resident flat Wout panel.
// fp32 transposed (B,C,N) store: [(b*512+col)*8000 + tok], float4.
// ---------------------------------------------------------------------------
__device__ __forceinline__ void ws_body512(
    const u16* __restrict__ A, const u16* __restrict__ Bp,
    const float* __restrict__ bias, float* __restrict__ Cf,
    int colBase, int mt)
{
    __shared__ u16 Bs[64 * 512];   // 64 KB
    int tid = threadIdx.x, lane = tid & 63, wv = tid >> 6;   // wv 0..7

#pragma unroll
    for (int c = 0; c < 8; c++) {
        int id = c * 512 + tid;
        int row = id >> 6, seg = id & 63;
        async16(Bp + (size_t)row * 512 + ((seg ^ (row & 7)) << 3),
                Bs + (size_t)id * 8);
    }

    int ml = lane & 15, quad = lane >> 4;
    int wm = (wv >> 1) * 64, wn = (wv & 1) * 32;   // 4x2 wave grid, 256x64

    int rowj[2];
#pragma unroll
    for (int j = 0; j < 2; j++) rowj[j] = wn + j * 16 + ml;

    __syncthreads();   // panel resident; vmcnt drained -> counts start clean

    int bm = mt * 256;
    const u16* Ap = A + ((size_t)((bm + wm) >> 4)) * 8192 + (size_t)lane * 8;

    f32x4 acc[4][2];
#pragma unroll
    for (int i = 0; i < 4; i++)
#pragma unroll
        for (int j = 0; j < 2; j++) acc[i][j] = (f32x4){0.f, 0.f, 0.f, 0.f};

    f32x4 afr[4][4];
    f16x8 bf[2][2];

#pragma unroll
    for (int kb = 0; kb < 3; kb++)
#pragma unroll
        for (int i = 0; i < 4; i++)
            afr[kb][i] = agload16(Ap + (size_t)i * 8192 + kb * 512);
#pragma unroll
    for (int j = 0; j < 2; j++)
        bf[0][j] = *reinterpret_cast<const f16x8*>(
            Bs + (size_t)rowj[j] * 512 + (((0 + quad) ^ (rowj[j] & 7)) << 3));

#pragma unroll
    for (int kk = 0; kk < 16; kk++) {
        if (kk + 3 < 16) {
#pragma unroll
            for (int i = 0; i < 4; i++)
                afr[(kk + 3) & 3][i] = agload16(
                    Ap + (size_t)i * 8192 + (kk + 3) * 512);
        }
        if (kk + 1 < 16) {
#pragma unroll
            for (int j = 0; j < 2; j++) {
                int seg = (kk + 1) * 4 + quad;
                bf[(kk + 1) & 1][j] = *reinterpret_cast<const f16x8*>(
                    Bs + (size_t)rowj[j] * 512 + ((seg ^ (rowj[j] & 7)) << 3));
            }
        }
        if (kk < 13)       VMWAIT(12);
        else if (kk == 13) VMWAIT(8);
        else if (kk == 14) VMWAIT(4);
        else               VMWAIT(0);
#pragma unroll
        for (int i = 0; i < 4; i++)
#pragma unroll
            for (int j = 0; j < 2; j++)
                acc[i][j] = __builtin_amdgcn_mfma_f32_16x16x32_f16(
                    __builtin_bit_cast(f16x8, afr[kk & 3][i]),
                    bf[kk & 1][j], acc[i][j], 0, 0, 0);
    }

#pragma unroll
    for (int i = 0; i < 4; i++) {
        int row = bm + wm + i * 16 + quad * 4;   // token index (4 consec)
        if (row >= BN_TOK) continue;             // tail tile guard
#pragma unroll
        for (int j = 0; j < 2; j++) {
            int col = colBase + wn + j * 16 + ml;
            float bia = bias[col];
            int bb = row >= 8000;
            float4 st;
            st.x = acc[i][j][0] + bia;
            st.y = acc[i][j][1] + bia;
            st.z = acc[i][j][2] + bia;
            st.w = acc[i][j][3] + bia;
            *reinterpret_cast<float4*>(
                Cf + ((size_t)(bb * 512 + col)) * 8000 + (row - bb * 8000)) = st;
        }
    }
}

// 512 flat blocks = 8 panels x 64 M-groups; same-XCD decode for A-reuse.
__global__ __launch_bounds__(512, 4) void gemm_out(
    const u16* __restrict__ A, const u16* __restrict__ WT,
    const float* __restrict__ bias, float* __restrict__ Cf)
{
    int did = blockIdx.x;                      // 0..511
    int m = ((did >> 6) << 3) | (did & 7);     // M-group 0..63
    if (m >= 63) return;                       // 63 tiles of 256 cover 16000
    int p = (did >> 3) & 7;                    // panel 0..7
    ws_body512(A, WT + (size_t)p * 64 * 512, bias, Cf, p * 64, m);
}

// ---------------------------------------------------------------------------
// Fused softmax + offset clip + trilinear sample + einsum, f16 volume.
// Output (sampled) stored in BLOCKED layout (consumed as A by out-GEMM).
// ---------------------------------------------------------------------------
__global__ __launch_bounds__(256) void sample_kernel(
    const u16* __restrict__ vol, const float* __restrict__ offb,
    const float* __restrict__ lgb, u16* __restrict__ outp)
{
    int wid = threadIdx.x >> 6, lane = threadIdx.x & 63;
    int bx = blockIdx.x;                               // 4000 = 8 slabs x 500
    int bn = ((bx & 7) * 500 + (bx >> 3)) * 4 + wid;   // token 0..15999
    int h = lane >> 3, cl = lane & 7;
    int b = bn / NTOK, n = bn - b * NTOK;
    int y = n / 400;
    int r2 = n - y * 400;
    int x = r2 / 20;
    int z = r2 - x * 20;

    const float* op = offb + (size_t)bn * 96 + h * 12;
    const float* lp = lgb + (size_t)bn * 32 + h * 4;
    float l0 = lp[0], l1 = lp[1], l2 = lp[2], l3 = lp[3];
    float mx = fmaxf(fmaxf(l0, l1), fmaxf(l2, l3));
    float e0 = expf(l0 - mx), e1 = expf(l1 - mx), e2 = expf(l2 - mx), e3 = expf(l3 - mx);
    float inv = 1.f / (e0 + e1 + e2 + e3);
    float at[4] = {e0 * inv, e1 * inv, e2 * inv, e3 * inv};

    const u16* volb = vol + b * (NTOK * C_DIM) + h * HDIM + cl * 8;
    h2 acc0 = (h2)(_Float16)0, acc1 = acc0, acc2 = acc0, acc3 = acc0;
#pragma unroll 1
    for (int p = 0; p < 4; p++) {
        float o0 = fminf(fmaxf(op[p * 3 + 0], -3.f), 3.f);
        float o1 = fminf(fmaxf(op[p * 3 + 1], -3.f), 3.f);
        float o2 = fminf(fmaxf(op[p * 3 + 2], -3.f), 3.f);
        float ix = fminf(fmaxf((float)y + o0, 0.f), 19.f);  // W axis
        float iy = fminf(fmaxf((float)x + o1, 0.f), 19.f);  // H axis
        float iz = fminf(fmaxf((float)z + o2, 0.f), 19.f);  // D axis
        float xf = floorf(ix), yf = floorf(iy), zf = floorf(iz);
        float fx = ix - xf, fy = iy - yf, fz = iz - zf;
        int x0 = (int)xf, y0 = (int)yf, z0 = (int)zf;
        int x1 = imin(x0 + 1, 19), y1 = imin(y0 + 1, 19), z1 = imin(z0 + 1, 19);
        int s00 = y0 * 400 + x0 * 20, s01 = y0 * 400 + x1 * 20;
        int s10 = y1 * 400 + x0 * 20, s11 = y1 * 400 + x1 * 20;
        uint4 v000 = *(const uint4*)(volb + (s00 + z0) * C_DIM);
        uint4 v001 = *(const uint4*)(volb + (s01 + z0) * C_DIM);
        uint4 v010 = *(const uint4*)(volb + (s10 + z0) * C_DIM);
        uint4 v011 = *(const uint4*)(volb + (s11 + z0) * C_DIM);
        uint4 v100 = *(const uint4*)(volb + (s00 + z1) * C_DIM);
        uint4 v101 = *(const uint4*)(volb + (s01 + z1) * C_DIM);
        uint4 v110 = *(const uint4*)(volb + (s10 + z1) * C_DIM);
        uint4 v111 = *(const uint4*)(volb + (s11 + z1) * C_DIM);
        float wz0 = (1.f - fz) * at[p], wz1 = fz * at[p];
        float w00 = wz0 * (1.f - fy), w01 = wz0 * fy;
        float w10 = wz1 * (1.f - fy), w11 = wz1 * fy;
        float gx0 = 1.f - fx;
        float cw[8] = { w00 * gx0, w00 * fx, w01 * gx0, w01 * fx,
                        w10 * gx0, w10 * fx, w11 * gx0, w11 * fx };
        const uint4* cv[8] = { &v000, &v001, &v010, &v011,
                               &v100, &v101, &v110, &v111 };
#pragma unroll
        for (int c = 0; c < 8; c++) {
            _Float16 wh = (_Float16)cw[c];
            h2 w2; w2.x = wh; w2.y = wh;
            uint4 d = *cv[c];
            acc0 += __builtin_bit_cast(h2, d.x) * w2;
            acc1 += __builtin_bit_cast(h2, d.y) * w2;
            acc2 += __builtin_bit_cast(h2, d.z) * w2;
            acc3 += __builtin_bit_cast(h2, d.w) * w2;
        }
    }
    uint4 o;
    o.x = __builtin_bit_cast(unsigned, acc0);
    o.y = __builtin_bit_cast(unsigned, acc1);
    o.z = __builtin_bit_cast(unsigned, acc2);
    o.w = __builtin_bit_cast(unsigned, acc3);
    *reinterpret_cast<uint4*>(outp + aidx(bn, h * HDIM + cl * 8)) = o;
}

// ---------------------------------------------------------------------------
// Launch
// ---------------------------------------------------------------------------
extern "C" void kernel_launch(void* const* d_in, const int* in_sizes, int n_in,
                              void* d_out, int out_size, void* d_ws, size_t ws_size,
                              hipStream_t stream)
{
    const float* f_query = (const float*)d_in[0];
    const float* f_kv    = (const float*)d_in[1];
    const float* ln_g    = (const float*)d_in[2];
    const float* ln_b    = (const float*)d_in[3];
    const float* Wq      = (const float*)d_in[4];
    const float* bq      = (const float*)d_in[5];
    const float* Wo1     = (const float*)d_in[6];
    const float* bo1     = (const float*)d_in[7];
    const float* Wo2     = (const float*)d_in[8];
    const float* bo2     = (const float*)d_in[9];
    const float* Wa      = (const float*)d_in[10];
    const float* ba      = (const float*)d_in[11];
    const float* Wout    = (const float*)d_in[12];
    const float* bout    = (const float*)d_in[13];
    float* out = (float*)d_out;

    float* ws = (float*)d_ws;
    float* offb = ws;                     // 1,536,000 f
    float* lgb  = ws + 1536000;           //   512,000 f
    u16* kvT   = (u16*)(ws + 2048000);    // 16000x512 (f16 channels-last)
    u16* qb    = kvT  + 8192000;          // 16000x512 (blocked: sampled out)
    u16* WqT   = qb   + 8192000;          // 512x512 blocked
    u16* Wo1T  = WqT + 262144;            // 512x512 blocked
    u16* WoutT = Wo1T + 262144;           // 512x512 flat
    u16* Wo2T  = WoutT + 262144;          // 128x512 blocked (96 valid)
    u16* WaT   = Wo2T + 65536;            // 128x512 blocked (32 valid)

    dim3 blk(256);
    dim3 blk512(512);
    // weight converts (blocked for mlp; flat for Wout)
    wcvt_all<<<dim3(16, 16, 5), blk, 0, stream>>>(
        Wq, WqT, Wo1, Wo1T, Wout, WoutT, Wo2, Wo2T, Wa, WaT);
    // f_kv (B,C,N) fp32 -> kvT (B,N,C) f16
    transpose_c2l_f16<<<dim3(250, 16, 2), blk, 0, stream>>>(f_kv, kvT);
    // fused LN -> Q -> hid -> off/logits (token-local chain, one dispatch)
    mlp_fused<<<dim3(250), blk512, 0, stream>>>(
        f_query, ln_g, ln_b, WqT, bq, Wo1T, bo1, Wo2T, bo2, WaT, ba,
        offb, lgb);
    // fused sample/softmax/einsum -> qb (f16 blocked)
    sample_kernel<<<dim3(4000), blk, 0, stream>>>(kvT, offb, lgb, qb);
    // out(B,C,N) = (sampled @ Wout + bout)^T
    gemm_out<<<dim3(512), blk512, 0, stream>>>(qb, WoutT, bout, out);
}

// Round 11
// 194.827 us; speedup vs baseline: 1.4644x; 1.0041x over previous
//
#include <hip/hip_runtime.h>
#include <math.h>

// Problem constants
#define C_DIM 512
#define NHEAD 8
#define HDIM 64
#define NTOK 8000
#define BN_TOK 16000

typedef __attribute__((ext_vector_type(8))) _Float16 f16x8;
typedef __attribute__((ext_vector_type(4))) float f32x4;
typedef __attribute__((ext_vector_type(2))) _Float16 h2;
typedef unsigned short u16;

__device__ __forceinline__ int imin(int a, int b) { return a < b ? a : b; }

// fp32 -> f16 (RNE)
__device__ __forceinline__ u16 f2h(float x) {
    _Float16 h = (_Float16)x;
    return __builtin_bit_cast(u16, h);
}

// MFMA-fragment-major blocked layout (R14, proven): token-major matrices.
// u16 index for (token t, channel c): block 16 tok x 512 ch = 8192 u16;
// a wave's 16x16x32 A-frag = base + lane*8 u16 -> one coalesced 1KB dwordx4.
__device__ __forceinline__ size_t aidx(int t, int c) {
    return ((size_t)(t >> 4)) * 8192 + (size_t)((c >> 5) * 512
         + (((c >> 3) & 3) * 128) + ((t & 15) * 8) + (c & 7));
}
// Same layout for weights as B-operand: (out-col n, k). Wave's B-frag for
// col-block cb, k-step kk = Wblk + cb*8192 + kk*512 + lane*8 (coalesced 1KB).
__device__ __forceinline__ size_t bidx(int n, int k) {
    return ((size_t)(n >> 4)) * 8192 + (size_t)((k >> 5) * 512
         + (((k >> 3) & 3) * 128) + ((n & 15) * 8) + (k & 7));
}

// async global->LDS, 16 bytes per lane (global_load_lds_dwordx4)
__device__ __forceinline__ void async16(const void* g, void* l) {
    __builtin_amdgcn_global_load_lds(
        (const __attribute__((address_space(1))) void*)g,
        (__attribute__((address_space(3))) void*)l, 16, 0, 0);
}

// compiler-proof 16B global load (asm volatile: un-sinkable, issue-ordered)
__device__ __forceinline__ f32x4 agload16(const u16* p) {
    f32x4 r;
    asm volatile("global_load_dwordx4 %0, %1, off" : "=v"(r) : "v"(p));
    return r;
}

// counted vmcnt + scheduler fence (rule #18). Extra compiler loads issued
// earlier only make the wait stricter (vmcnt drains in issue order) -> safe.
#define VMWAIT(N) do { asm volatile("s_waitcnt vmcnt(" #N ")"); \
                       __builtin_amdgcn_sched_barrier(0); } while (0)

// ---------------------------------------------------------------------------
// f_kv (B,C,N) fp32 -> kvT (B,N,C) f16. Fixed 512 x 8000 per batch.
// (kvT stays channels-contiguous row-major: consumed by sample gather.)
// ---------------------------------------------------------------------------
__global__ __launch_bounds__(256) void transpose_c2l_f16(
    const float* __restrict__ in, u16* __restrict__ out)
{
    __shared__ float tile[32][33];
    int b = blockIdx.z;
    const float* inb = in + (size_t)b * 512 * NTOK;
    u16* outb = out + (size_t)b * NTOK * 512;
    int s0 = blockIdx.x * 32, r0 = blockIdx.y * 32;   // s: token, r: channel
    int tx = threadIdx.x & 31, ty = threadIdx.x >> 5;
#pragma unroll
    for (int i = 0; i < 4; i++)
        tile[ty + i * 8][tx] = inb[(size_t)(r0 + ty + i * 8) * NTOK + s0 + tx];
    __syncthreads();
    int rq = threadIdx.x & 7, sy = threadIdx.x >> 3;  // rq: channel quad, sy: token
    ushort4 o;
    o.x = f2h(tile[rq * 4 + 0][sy]);
    o.y = f2h(tile[rq * 4 + 1][sy]);
    o.z = f2h(tile[rq * 4 + 2][sy]);
    o.w = f2h(tile[rq * 4 + 3][sy]);
    *reinterpret_cast<ushort4*>(outb + (size_t)(s0 + sy) * 512 + r0 + rq * 4) = o;
}

// ---------------------------------------------------------------------------
// Weight converts. z: 0 Wq(blocked) 1 Wo1(blocked) 2 Wout(FLAT N^T x K,
// staged to LDS by out-GEMM) 3 Wo2(blocked) 4 Wa(blocked). Pad rows zeroed.
// ---------------------------------------------------------------------------
__global__ __launch_bounds__(256) void wcvt_all(
    const float* __restrict__ W0, u16* __restrict__ T0,
    const float* __restrict__ W1, u16* __restrict__ T1,
    const float* __restrict__ W2, u16* __restrict__ T2,
    const float* __restrict__ W3, u16* __restrict__ T3,
    const float* __restrict__ W4, u16* __restrict__ T4)
{
    const float* W; u16* Wt; int Nout, Npad;
    switch (blockIdx.z) {
        case 0: W = W0; Wt = T0; Nout = 512; Npad = 512; break;
        case 1: W = W1; Wt = T1; Nout = 512; Npad = 512; break;
        case 2: W = W2; Wt = T2; Nout = 512; Npad = 512; break;
        case 3: W = W3; Wt = T3; Nout = 96;  Npad = 128; break;
        default: W = W4; Wt = T4; Nout = 32; Npad = 128; break;
    }
    int blocked = (blockIdx.z != 2);
    int n0 = blockIdx.x * 32, k0 = blockIdx.y * 32;
    if (n0 >= Npad) return;
    __shared__ float t[32][33];
    int tx = threadIdx.x & 31, ty = threadIdx.x >> 5;
#pragma unroll
    for (int i = 0; i < 4; i++) {
        int k = k0 + ty + i * 8, n = n0 + tx;
        t[ty + i * 8][tx] = (n < Nout) ? W[(size_t)k * Nout + n] : 0.f;
    }
    __syncthreads();
#pragma unroll
    for (int i = 0; i < 4; i++) {
        int n = n0 + ty + i * 8, k = k0 + tx;
        u16 v = f2h(t[tx][ty + i * 8]);
        if (blocked) Wt[bidx(n, k)] = v;
        else         Wt[(size_t)n * 512 + k] = v;
    }
}

// ---------------------------------------------------------------------------
// R19: fused MLP (R17 geometry, measured-good) + two micro-levers:
// (a) SINGLE f_query read: thread holds its 64 input values in registers
//     (static indexing after full unroll, rule #20), stats from regs,
//     normalize from regs -> T0. Removes the second 64MB pass (L3-absorbed
//     per R8 FETCH=28MB, so this buys L3 time + kills a serial phase).
// (b) B-ring 4-deep (12 in flight, VMWAIT(12/8/4/0)): at 2 waves/SIMD,
//     3-ahead x 77cyc MFMA/batch ~ covers the ~300cyc L2 latency.
// Geometry unchanged: 64-token blocks x 250, 8 waves, wave owns 64 cols x
// all 64 tokens; block reads each weight matrix once (1.15MB/CU).
// ---------------------------------------------------------------------------
__device__ __forceinline__ void lds_gemm64(
    const u16* Tin, u16* Tout, const u16* __restrict__ Wblk,
    const float* __restrict__ bias, int relu, int lane, int wv)
{
    int ml = lane & 15, quad = lane >> 4;
    int c0 = wv * 64;                       // wave's 64-col slice
    const u16* Bp = Wblk + (size_t)(c0 >> 4) * 8192 + (size_t)lane * 8;

    f32x4 acc[4][4];
#pragma unroll
    for (int t = 0; t < 4; t++)
#pragma unroll
        for (int j = 0; j < 4; j++) acc[t][j] = (f32x4){0.f, 0.f, 0.f, 0.f};

    f32x4 bfr[4][4];   // ring [batch&3][j], 3 batches ahead (12 in flight)
#pragma unroll
    for (int kb = 0; kb < 3; kb++)
#pragma unroll
        for (int j = 0; j < 4; j++)
            bfr[kb][j] = agload16(Bp + (size_t)j * 8192 + kb * 512);

#pragma unroll
    for (int kk = 0; kk < 16; kk++) {
        if (kk + 3 < 16) {
#pragma unroll
            for (int j = 0; j < 4; j++)
                bfr[(kk + 3) & 3][j] = agload16(
                    Bp + (size_t)j * 8192 + (kk + 3) * 512);
        }
        f16x8 a[4];
#pragma unroll
        for (int t = 0; t < 4; t++)
            a[t] = *reinterpret_cast<const f16x8*>(
                Tin + (t * 16 + ml) * 520 + (kk * 4 + quad) * 8);
        if (kk < 13)       VMWAIT(12);
        else if (kk == 13) VMWAIT(8);
        else if (kk == 14) VMWAIT(4);
        else               VMWAIT(0);
#pragma unroll
        for (int j = 0; j < 4; j++) {
            f16x8 bj = __builtin_bit_cast(f16x8, bfr[kk & 3][j]);
#pragma unroll
            for (int t = 0; t < 4; t++)
                acc[t][j] = __builtin_amdgcn_mfma_f32_16x16x32_f16(
                    a[t], bj, acc[t][j], 0, 0, 0);
        }
    }

    // C/D: col=lane&15, row=quad*4+reg (m89/m91)
#pragma unroll
    for (int t = 0; t < 4; t++)
#pragma unroll
        for (int j = 0; j < 4; j++) {
            int col = c0 + j * 16 + ml;
            float bia = bias[col];
#pragma unroll
            for (int rg = 0; rg < 4; rg++) {
                float v = acc[t][j][rg] + bia;
                if (relu) v = fmaxf(v, 0.f);
                Tout[(t * 16 + quad * 4 + rg) * 520 + col] = f2h(v);
            }
        }
}

__global__ __launch_bounds__(512, 2) void mlp_fused(
    const float* __restrict__ fq, const float* __restrict__ gamma,
    const float* __restrict__ beta,
    const u16* __restrict__ Wqb, const float* __restrict__ bq,
    const u16* __restrict__ Wo1b, const float* __restrict__ bo1,
    const u16* __restrict__ Wo2b, const float* __restrict__ bo2,
    const u16* __restrict__ Wab, const float* __restrict__ ba,
    float* __restrict__ offb, float* __restrict__ lgb)
{
    __shared__ u16 T0[64 * 520], T1[64 * 520];     // 133.1 KB
    __shared__ float ps[64][9], pq[64][9];
    __shared__ float muA[64], rsA[64];
    int tid = threadIdx.x, lane = tid & 63, wv = tid >> 6;
    int blk = blockIdx.x;                // 250 blocks; 125 per batch (exact)
    int tp = tid & 63;                   // token in tile
    int cg = tid >> 6;                   // 0..7 chunk-group
    int b = blk >= 125;
    int n0 = (blk - b * 125) * 64;
    const float* src = fq + (size_t)b * C_DIM * NTOK + n0 + tp;

    // ---- LN: single global read; values held in regs (static idx) ----
    float vals[64];
    {
        float s = 0.f, q = 0.f;
#pragma unroll
        for (int it = 0; it < 8; ++it) {
            int c0 = (cg + it * 8) * 8;
#pragma unroll
            for (int e = 0; e < 8; ++e) {
                float v = src[(size_t)(c0 + e) * NTOK];
                vals[it * 8 + e] = v;
                s += v; q += v * v;
            }
        }
        ps[tp][cg] = s; pq[tp][cg] = q;
    }
    __syncthreads();
    if (tid < 64) {
        float S = 0.f, SQ = 0.f;
#pragma unroll
        for (int g = 0; g < 8; ++g) { S += ps[tid][g]; SQ += pq[tid][g]; }
        float mu = S * (1.f / 512.f);
        muA[tid] = mu;
        rsA[tid] = rsqrtf(SQ * (1.f / 512.f) - mu * mu + 1e-5f);
    }
    __syncthreads();
    // ---- LN apply from registers, pack 8ch -> one b128 LDS store ----
    {
        float mu = muA[tp], rs = rsA[tp];
#pragma unroll
        for (int it = 0; it < 8; ++it) {
            int c0 = (cg + it * 8) * 8;
            u16 o[8];
#pragma unroll
            for (int e = 0; e < 8; ++e)
                o[e] = f2h((vals[it * 8 + e] - mu) * rs * gamma[c0 + e]
                           + beta[c0 + e]);
            *reinterpret_cast<f16x8*>(&T0[tp * 520 + c0]) =
                *reinterpret_cast<const f16x8*>(o);
        }
    }
    __syncthreads();
    // ---- Q = q @ Wq + bq : T0 -> T1 ----
    lds_gemm64(T0, T1, Wqb, bq, 0, lane, wv);
    __syncthreads();
    // ---- hid = relu(Q @ Wo1 + bo1) : T1 -> T0 ----
    lds_gemm64(T1, T0, Wo1b, bo1, 1, lane, wv);
    __syncthreads();
    // ---- off (waves 0-5: hid@Wo2, 96 cols) & logits (waves 6-7: Q@Wa) ----
    {
        int ml = lane & 15, quad = lane >> 4;
        int isLg = wv >= 6;
        int cb = isLg ? (wv - 6) : wv;             // 16-col block
        const u16* Tin = isLg ? T1 : T0;
        const u16* Wsm = isLg ? Wab : Wo2b;
        const float* bs = isLg ? ba : bo2;
        float* outg = isLg ? lgb : offb;
        int ldo = isLg ? 32 : 96;
        // preload wave's full 16-col x 512-K weight panel to registers
        const u16* Wp = Wsm + (size_t)cb * 8192 + (size_t)lane * 8;
        f16x8 wb[16];
#pragma unroll
        for (int kk = 0; kk < 16; kk++)
            wb[kk] = *reinterpret_cast<const f16x8*>(Wp + (size_t)kk * 512);
        float bia = bs[cb * 16 + ml];
        int tbase = blk * 64;
#pragma unroll
        for (int tg = 0; tg < 4; tg++) {
            f32x4 acc = (f32x4){0.f, 0.f, 0.f, 0.f};
            const u16* Ar = Tin + (tg * 16 + ml) * 520;
#pragma unroll
            for (int kk = 0; kk < 16; kk++) {
                f16x8 af = *reinterpret_cast<const f16x8*>(
                    Ar + (kk * 4 + quad) * 8);
                acc = __builtin_amdgcn_mfma_f32_16x16x32_f16(
                    af, wb[kk], acc, 0, 0, 0);
            }
#pragma unroll
            for (int rg = 0; rg < 4; rg++)
                outg[(size_t)(tbase + tg * 16 + quad * 4 + rg) * ldo
                     + cb * 16 + ml] = acc[rg] + bia;
        }
    }
}

// ---------------------------------------------------------------------------
// Weight-stationary out-GEMM (R14, unchanged): blocked-A coalesced frag
// loads + asm ring + counted vmcnt; 64KB resident flat Wout panel.
// fp32 transposed (B,C,N) store: [(b*512+col)*8000 + tok], float4.
// ---------------------------------------------------------------------------
__device__ __forceinline__ void ws_body512(
    const u16* __restrict__ A, const u16* __restrict__ Bp,
    const float* __restrict__ bias, float* __restrict__ Cf,
    int colBase, int mt)
{
    __shared__ u16 Bs[64 * 512];   // 64 KB
    int tid = threadIdx.x, lane = tid & 63, wv = tid >> 6;   // wv 0..7

#pragma unroll
    for (int c = 0; c < 8; c++) {
        int id = c * 512 + tid;
        int row = id >> 6, seg = id & 63;
        async16(Bp + (size_t)row * 512 + ((seg ^ (row & 7)) << 3),
                Bs + (size_t)id * 8);
    }

    int ml = lane & 15, quad = lane >> 4;
    int wm = (wv >> 1) * 64, wn = (wv & 1) * 32;   // 4x2 wave grid, 256x64

    int rowj[2];
#pragma unroll
    for (int j = 0; j < 2; j++) rowj[j] = wn + j * 16 + ml;

    __syncthreads();   // panel resident; vmcnt drained -> counts start clean

    int bm = mt * 256;
    const u16* Ap = A + ((size_t)((bm + wm) >> 4)) * 8192 + (size_t)lane * 8;

    f32x4 acc[4][2];
#pragma unroll
    for (int i = 0; i < 4; i++)
#pragma unroll
        for (int j = 0; j < 2; j++) acc[i][j] = (f32x4){0.f, 0.f, 0.f, 0.f};

    f32x4 afr[4][4];
    f16x8 bf[2][2];

#pragma unroll
    for (int kb = 0; kb < 3; kb++)
#pragma unroll
        for (int i = 0; i < 4; i++)
            afr[kb][i] = agload16(Ap + (size_t)i * 8192 + kb * 512);
#pragma unroll
    for (int j = 0; j < 2; j++)
        bf[0][j] = *reinterpret_cast<const f16x8*>(
            Bs + (size_t)rowj[j] * 512 + (((0 + quad) ^ (rowj[j] & 7)) << 3));

#pragma unroll
    for (int kk = 0; kk < 16; kk++) {
        if (kk + 3 < 16) {
#pragma unroll
            for (int i = 0; i < 4; i++)
                afr[(kk + 3) & 3][i] = agload16(
                    Ap + (size_t)i * 8192 + (kk + 3) * 512);
        }
        if (kk + 1 < 16) {
#pragma unroll
            for (int j = 0; j < 2; j++) {
                int seg = (kk + 1) * 4 + quad;
                bf[(kk + 1) & 1][j] = *reinterpret_cast<const f16x8*>(
                    Bs + (size_t)rowj[j] * 512 + ((seg ^ (rowj[j] & 7)) << 3));
            }
        }
        if (kk < 13)       VMWAIT(12);
        else if (kk == 13) VMWAIT(8);
        else if (kk == 14) VMWAIT(4);
        else               VMWAIT(0);
#pragma unroll
        for (int i = 0; i < 4; i++)
#pragma unroll
            for (int j = 0; j < 2; j++)
                acc[i][j] = __builtin_amdgcn_mfma_f32_16x16x32_f16(
                    __builtin_bit_cast(f16x8, afr[kk & 3][i]),
                    bf[kk & 1][j], acc[i][j], 0, 0, 0);
    }

#pragma unroll
    for (int i = 0; i < 4; i++) {
        int row = bm + wm + i * 16 + quad * 4;   // token index (4 consec)
        if (row >= BN_TOK) continue;             // tail tile guard
#pragma unroll
        for (int j = 0; j < 2; j++) {
            int col = colBase + wn + j * 16 + ml;
            float bia = bias[col];
            int bb = row >= 8000;
            float4 st;
            st.x = acc[i][j][0] + bia;
            st.y = acc[i][j][1] + bia;
            st.z = acc[i][j][2] + bia;
            st.w = acc[i][j][3] + bia;
            *reinterpret_cast<float4*>(
                Cf + ((size_t)(bb * 512 + col)) * 8000 + (row - bb * 8000)) = st;
        }
    }
}

// 512 flat blocks = 8 panels x 64 M-groups; same-XCD decode for A-reuse.
__global__ __launch_bounds__(512, 4) void gemm_out(
    const u16* __restrict__ A, const u16* __restrict__ WT,
    const float* __restrict__ bias, float* __restrict__ Cf)
{
    int did = blockIdx.x;                      // 0..511
    int m = ((did >> 6) << 3) | (did & 7);     // M-group 0..63
    if (m >= 63) return;                       // 63 tiles of 256 cover 16000
    int p = (did >> 3) & 7;                    // panel 0..7
    ws_body512(A, WT + (size_t)p * 64 * 512, bias, Cf, p * 64, m);
}

// ---------------------------------------------------------------------------
// Fused softmax + offset clip + trilinear sample + einsum, f16 volume.
// Output (sampled) stored in BLOCKED layout (consumed as A by out-GEMM).
// ---------------------------------------------------------------------------
__global__ __launch_bounds__(256) void sample_kernel(
    const u16* __restrict__ vol, const float* __restrict__ offb,
    const float* __restrict__ lgb, u16* __restrict__ outp)
{
    int wid = threadIdx.x >> 6, lane = threadIdx.x & 63;
    int bx = blockIdx.x;                               // 4000 = 8 slabs x 500
    int bn = ((bx & 7) * 500 + (bx >> 3)) * 4 + wid;   // token 0..15999
    int h = lane >> 3, cl = lane & 7;
    int b = bn / NTOK, n = bn - b * NTOK;
    int y = n / 400;
    int r2 = n - y * 400;
    int x = r2 / 20;
    int z = r2 - x * 20;

    const float* op = offb + (size_t)bn * 96 + h * 12;
    const float* lp = lgb + (size_t)bn * 32 + h * 4;
    float l0 = lp[0], l1 = lp[1], l2 = lp[2], l3 = lp[3];
    float mx = fmaxf(fmaxf(l0, l1), fmaxf(l2, l3));
    float e0 = expf(l0 - mx), e1 = expf(l1 - mx), e2 = expf(l2 - mx), e3 = expf(l3 - mx);
    float inv = 1.f / (e0 + e1 + e2 + e3);
    float at[4] = {e0 * inv, e1 * inv, e2 * inv, e3 * inv};

    const u16* volb = vol + b * (NTOK * C_DIM) + h * HDIM + cl * 8;
    h2 acc0 = (h2)(_Float16)0, acc1 = acc0, acc2 = acc0, acc3 = acc0;
#pragma unroll 1
    for (int p = 0; p < 4; p++) {
        float o0 = fminf(fmaxf(op[p * 3 + 0], -3.f), 3.f);
        float o1 = fminf(fmaxf(op[p * 3 + 1], -3.f), 3.f);
        float o2 = fminf(fmaxf(op[p * 3 + 2], -3.f), 3.f);
        float ix = fminf(fmaxf((float)y + o0, 0.f), 19.f);  // W axis
        float iy = fminf(fmaxf((float)x + o1, 0.f), 19.f);  // H axis
        float iz = fminf(fmaxf((float)z + o2, 0.f), 19.f);  // D axis
        float xf = floorf(ix), yf = floorf(iy), zf = floorf(iz);
        float fx = ix - xf, fy = iy - yf, fz = iz - zf;
        int x0 = (int)xf, y0 = (int)yf, z0 = (int)zf;
        int x1 = imin(x0 + 1, 19), y1 = imin(y0 + 1, 19), z1 = imin(z0 + 1, 19);
        int s00 = y0 * 400 + x0 * 20, s01 = y0 * 400 + x1 * 20;
        int s10 = y1 * 400 + x0 * 20, s11 = y1 * 400 + x1 * 20;
        uint4 v000 = *(const uint4*)(volb + (s00 + z0) * C_DIM);
        uint4 v001 = *(const uint4*)(volb + (s01 + z0) * C_DIM);
        uint4 v010 = *(const uint4*)(volb + (s10 + z0) * C_DIM);
        uint4 v011 = *(const uint4*)(volb + (s11 + z0) * C_DIM);
        uint4 v100 = *(const uint4*)(volb + (s00 + z1) * C_DIM);
        uint4 v101 = *(const uint4*)(volb + (s01 + z1) * C_DIM);
        uint4 v110 = *(const uint4*)(volb + (s10 + z1) * C_DIM);
        uint4 v111 = *(const uint4*)(volb + (s11 + z1) * C_DIM);
        float wz0 = (1.f - fz) * at[p], wz1 = fz * at[p];
        float w00 = wz0 * (1.f - fy), w01 = wz0 * fy;
        float w10 = wz1 * (1.f - fy), w11 = wz1 * fy;
        float gx0 = 1.f - fx;
        float cw[8] = { w00 * gx0, w00 * fx, w01 * gx0, w01 * fx,
                        w10 * gx0, w10 * fx, w11 * gx0, w11 * fx };
        const uint4* cv[8] = { &v000, &v001, &v010, &v011,
                               &v100, &v101, &v110, &v111 };
#pragma unroll
        for (int c = 0; c < 8; c++) {
            _Float16 wh = (_Float16)cw[c];
            h2 w2; w2.x = wh; w2.y = wh;
            uint4 d = *cv[c];
            acc0 += __builtin_bit_cast(h2, d.x) * w2;
            acc1 += __builtin_bit_cast(h2, d.y) * w2;
            acc2 += __builtin_bit_cast(h2, d.z) * w2;
            acc3 += __builtin_bit_cast(h2, d.w) * w2;
        }
    }
    uint4 o;
    o.x = __builtin_bit_cast(unsigned, acc0);
    o.y = __builtin_bit_cast(unsigned, acc1);
    o.z = __builtin_bit_cast(unsigned, acc2);
    o.w = __builtin_bit_cast(unsigned, acc3);
    *reinterpret_cast<uint4*>(outp + aidx(bn, h * HDIM + cl * 8)) = o;
}

// ---------------------------------------------------------------------------
// Launch
// ---------------------------------------------------------------------------
extern "C" void kernel_launch(void* const* d_in, const int* in_sizes, int n_in,
                              void* d_out, int out_size, void* d_ws, size_t ws_size,
                              hipStream_t stream)
{
    const float* f_query = (const float*)d_in[0];
    const float* f_kv    = (const float*)d_in[1];
    const float* ln_g    = (const float*)d_in[2];
    const float* ln_b    = (const float*)d_in[3];
    const float* Wq      = (const float*)d_in[4];
    const float* bq      = (const float*)d_in[5];
    const float* Wo1     = (const float*)d_in[6];
    const float* bo1     = (const float*)d_in[7];
    const float* Wo2     = (const float*)d_in[8];
    const float* bo2     = (const float*)d_in[9];
    const float* Wa      = (const float*)d_in[10];
    const float* ba      = (const float*)d_in[11];
    const float* Wout    = (const float*)d_in[12];
    const float* bout    = (const float*)d_in[13];
    float* out = (float*)d_out;

    float* ws = (float*)d_ws;
    float* offb = ws;                     // 1,536,000 f
    float* lgb  = ws + 1536000;           //   512,000 f
    u16* kvT   = (u16*)(ws + 2048000);    // 16000x512 (f16 channels-last)
    u16* qb    = kvT  + 8192000;          // 16000x512 (blocked: sampled out)
    u16* WqT   = qb   + 8192000;          // 512x512 blocked
    u16* Wo1T  = WqT + 262144;            // 512x512 blocked
    u16* WoutT = Wo1T + 262144;           // 512x512 flat
    u16* Wo2T  = WoutT + 262144;          // 128x512 blocked (96 valid)
    u16* WaT   = Wo2T + 65536;            // 128x512 blocked (32 valid)

    dim3 blk(256);
    dim3 blk512(512);
    // weight converts (blocked for mlp; flat for Wout)
    wcvt_all<<<dim3(16, 16, 5), blk, 0, stream>>>(
        Wq, WqT, Wo1, Wo1T, Wout, WoutT, Wo2, Wo2T, Wa, WaT);
    // f_kv (B,C,N) fp32 -> kvT (B,N,C) f16
    transpose_c2l_f16<<<dim3(250, 16, 2), blk, 0, stream>>>(f_kv, kvT);
    // fused LN -> Q -> hid -> off/logits (token-local chain, one dispatch)
    mlp_fused<<<dim3(250), blk512, 0, stream>>>(
        f_query, ln_g, ln_b, WqT, bq, Wo1T, bo1, Wo2T, bo2, WaT, ba,
        offb, lgb);
    // fused sample/softmax/einsum -> qb (f16 blocked)
    sample_kernel<<<dim3(4000), blk, 0, stream>>>(kvT, offb, lgb, qb);
    // out(B,C,N) = (sampled @ Wout + bout)^T
    gemm_out<<<dim3(512), blk512, 0, stream>>>(qb, WoutT, bout, out);
}

// Round 12
// 179.552 us; speedup vs baseline: 1.5890x; 1.0851x over previous
//
#include <hip/hip_runtime.h>
#include <math.h>

// Problem constants
#define C_DIM 512
#define NHEAD 8
#define HDIM 64
#define NTOK 8000
#define BN_TOK 16000

typedef __attribute__((ext_vector_type(8))) _Float16 f16x8;
typedef __attribute__((ext_vector_type(4))) float f32x4;
typedef __attribute__((ext_vector_type(2))) _Float16 h2;
typedef unsigned short u16;

__device__ __forceinline__ int imin(int a, int b) { return a < b ? a : b; }

// fp32 -> f16 (RNE)
__device__ __forceinline__ u16 f2h(float x) {
    _Float16 h = (_Float16)x;
    return __builtin_bit_cast(u16, h);
}

// Fragment-major blocked layout for weights as B-operand (R14, proven):
// (out-col n, k). Wave's B-frag for col-block cb, k-step kk =
// Wblk + cb*8192 + kk*512 + lane*8 -> one coalesced 1KB dwordx4.
__device__ __forceinline__ size_t bidx(int n, int k) {
    return ((size_t)(n >> 4)) * 8192 + (size_t)((k >> 5) * 512
         + (((k >> 3) & 3) * 128) + ((n & 15) * 8) + (k & 7));
}

// compiler-proof 16B global load (asm volatile: un-sinkable, issue-ordered)
__device__ __forceinline__ f32x4 agload16(const u16* p) {
    f32x4 r;
    asm volatile("global_load_dwordx4 %0, %1, off" : "=v"(r) : "v"(p));
    return r;
}

// counted vmcnt + scheduler fence (rule #18). Extra compiler loads issued
// earlier only make the wait stricter (vmcnt drains in issue order) -> safe.
#define VMWAIT(N) do { asm volatile("s_waitcnt vmcnt(" #N ")"); \
                       __builtin_amdgcn_sched_barrier(0); } while (0)

// ---------------------------------------------------------------------------
// R20 prep_all: f_kv transpose (8000 blocks) + all 5 weight converts (1280
// blocks) in ONE flat 9280-block dispatch (was 2 dispatches). All weights
// now BLOCKED (bidx) — Wout too, since sample_out consumes it via the
// blocked B-ring.
// ---------------------------------------------------------------------------
__global__ __launch_bounds__(256) void prep_all(
    const float* __restrict__ f_kv, u16* __restrict__ kvT,
    const float* __restrict__ W0, u16* __restrict__ T0w,
    const float* __restrict__ W1, u16* __restrict__ T1w,
    const float* __restrict__ W2, u16* __restrict__ T2w,
    const float* __restrict__ W3, u16* __restrict__ T3w,
    const float* __restrict__ W4, u16* __restrict__ T4w)
{
    __shared__ float tile[32][33];
    int id = blockIdx.x;
    if (id < 8000) {
        // f_kv (B,C,N) fp32 -> kvT (B,N,C) f16, 32x32 tiles
        int b = id / 4000, r = id - b * 4000;
        int s0 = (r % 250) * 32, r0 = (r / 250) * 32;   // s: token, r: chan
        const float* inb = f_kv + (size_t)b * 512 * NTOK;
        u16* outb = kvT + (size_t)b * NTOK * 512;
        int tx = threadIdx.x & 31, ty = threadIdx.x >> 5;
#pragma unroll
        for (int i = 0; i < 4; i++)
            tile[ty + i * 8][tx] =
                inb[(size_t)(r0 + ty + i * 8) * NTOK + s0 + tx];
        __syncthreads();
        int rq = threadIdx.x & 7, sy = threadIdx.x >> 3;
        ushort4 o;
        o.x = f2h(tile[rq * 4 + 0][sy]);
        o.y = f2h(tile[rq * 4 + 1][sy]);
        o.z = f2h(tile[rq * 4 + 2][sy]);
        o.w = f2h(tile[rq * 4 + 3][sy]);
        *reinterpret_cast<ushort4*>(
            outb + (size_t)(s0 + sy) * 512 + r0 + rq * 4) = o;
    } else {
        // weight convert, all blocked. id2: z*256 + (y*16 + x)
        int id2 = id - 8000;
        int z = id2 >> 8, xy = id2 & 255;
        int n0 = (xy & 15) * 32, k0 = (xy >> 4) * 32;
        const float* W; u16* Wt; int Nout, Npad;
        switch (z) {
            case 0: W = W0; Wt = T0w; Nout = 512; Npad = 512; break;
            case 1: W = W1; Wt = T1w; Nout = 512; Npad = 512; break;
            case 2: W = W2; Wt = T2w; Nout = 512; Npad = 512; break;
            case 3: W = W3; Wt = T3w; Nout = 96;  Npad = 128; break;
            default: W = W4; Wt = T4w; Nout = 32; Npad = 128; break;
        }
        if (n0 >= Npad) return;
        int tx = threadIdx.x & 31, ty = threadIdx.x >> 5;
#pragma unroll
        for (int i = 0; i < 4; i++) {
            int k = k0 + ty + i * 8, n = n0 + tx;
            tile[ty + i * 8][tx] = (n < Nout) ? W[(size_t)k * Nout + n] : 0.f;
        }
        __syncthreads();
#pragma unroll
        for (int i = 0; i < 4; i++) {
            int n = n0 + ty + i * 8, k = k0 + tx;
            Wt[bidx(n, k)] = f2h(tile[tx][ty + i * 8]);
        }
    }
}

// ---------------------------------------------------------------------------
// Fused MLP (R19, measured-good; unchanged): LN -> Q -> hid -> off/logits.
// 64-token blocks x 250, 8 waves; wave owns 64 cols x all 64 tokens;
// block reads each weight matrix once (1.15MB/CU); B-ring 4-deep asm +
// counted vmcnt; single f_query read (values in regs).
// ---------------------------------------------------------------------------
__device__ __forceinline__ void lds_gemm64(
    const u16* Tin, u16* Tout, const u16* __restrict__ Wblk,
    const float* __restrict__ bias, int relu, int lane, int wv)
{
    int ml = lane & 15, quad = lane >> 4;
    int c0 = wv * 64;                       // wave's 64-col slice
    const u16* Bp = Wblk + (size_t)(c0 >> 4) * 8192 + (size_t)lane * 8;

    f32x4 acc[4][4];
#pragma unroll
    for (int t = 0; t < 4; t++)
#pragma unroll
        for (int j = 0; j < 4; j++) acc[t][j] = (f32x4){0.f, 0.f, 0.f, 0.f};

    f32x4 bfr[4][4];   // ring [batch&3][j], 3 batches ahead (12 in flight)
#pragma unroll
    for (int kb = 0; kb < 3; kb++)
#pragma unroll
        for (int j = 0; j < 4; j++)
            bfr[kb][j] = agload16(Bp + (size_t)j * 8192 + kb * 512);

#pragma unroll
    for (int kk = 0; kk < 16; kk++) {
        if (kk + 3 < 16) {
#pragma unroll
            for (int j = 0; j < 4; j++)
                bfr[(kk + 3) & 3][j] = agload16(
                    Bp + (size_t)j * 8192 + (kk + 3) * 512);
        }
        f16x8 a[4];
#pragma unroll
        for (int t = 0; t < 4; t++)
            a[t] = *reinterpret_cast<const f16x8*>(
                Tin + (t * 16 + ml) * 520 + (kk * 4 + quad) * 8);
        if (kk < 13)       VMWAIT(12);
        else if (kk == 13) VMWAIT(8);
        else if (kk == 14) VMWAIT(4);
        else               VMWAIT(0);
#pragma unroll
        for (int j = 0; j < 4; j++) {
            f16x8 bj = __builtin_bit_cast(f16x8, bfr[kk & 3][j]);
#pragma unroll
            for (int t = 0; t < 4; t++)
                acc[t][j] = __builtin_amdgcn_mfma_f32_16x16x32_f16(
                    a[t], bj, acc[t][j], 0, 0, 0);
        }
    }

    // C/D: col=lane&15, row=quad*4+reg (m89/m91)
#pragma unroll
    for (int t = 0; t < 4; t++)
#pragma unroll
        for (int j = 0; j < 4; j++) {
            int col = c0 + j * 16 + ml;
            float bia = bias[col];
#pragma unroll
            for (int rg = 0; rg < 4; rg++) {
                float v = acc[t][j][rg] + bia;
                if (relu) v = fmaxf(v, 0.f);
                Tout[(t * 16 + quad * 4 + rg) * 520 + col] = f2h(v);
            }
        }
}

__global__ __launch_bounds__(512, 2) void mlp_fused(
    const float* __restrict__ fq, const float* __restrict__ gamma,
    const float* __restrict__ beta,
    const u16* __restrict__ Wqb, const float* __restrict__ bq,
    const u16* __restrict__ Wo1b, const float* __restrict__ bo1,
    const u16* __restrict__ Wo2b, const float* __restrict__ bo2,
    const u16* __restrict__ Wab, const float* __restrict__ ba,
    float* __restrict__ offb, float* __restrict__ lgb)
{
    __shared__ u16 T0[64 * 520], T1[64 * 520];     // 133.1 KB
    __shared__ float ps[64][9], pq[64][9];
    __shared__ float muA[64], rsA[64];
    int tid = threadIdx.x, lane = tid & 63, wv = tid >> 6;
    int blk = blockIdx.x;                // 250 blocks; 125 per batch (exact)
    int tp = tid & 63;                   // token in tile
    int cg = tid >> 6;                   // 0..7 chunk-group
    int b = blk >= 125;
    int n0 = (blk - b * 125) * 64;
    const float* src = fq + (size_t)b * C_DIM * NTOK + n0 + tp;

    // ---- LN: single global read; values held in regs (static idx) ----
    float vals[64];
    {
        float s = 0.f, q = 0.f;
#pragma unroll
        for (int it = 0; it < 8; ++it) {
            int c0 = (cg + it * 8) * 8;
#pragma unroll
            for (int e = 0; e < 8; ++e) {
                float v = src[(size_t)(c0 + e) * NTOK];
                vals[it * 8 + e] = v;
                s += v; q += v * v;
            }
        }
        ps[tp][cg] = s; pq[tp][cg] = q;
    }
    __syncthreads();
    if (tid < 64) {
        float S = 0.f, SQ = 0.f;
#pragma unroll
        for (int g = 0; g < 8; ++g) { S += ps[tid][g]; SQ += pq[tid][g]; }
        float mu = S * (1.f / 512.f);
        muA[tid] = mu;
        rsA[tid] = rsqrtf(SQ * (1.f / 512.f) - mu * mu + 1e-5f);
    }
    __syncthreads();
    // ---- LN apply from registers, pack 8ch -> one b128 LDS store ----
    {
        float mu = muA[tp], rs = rsA[tp];
#pragma unroll
        for (int it = 0; it < 8; ++it) {
            int c0 = (cg + it * 8) * 8;
            u16 o[8];
#pragma unroll
            for (int e = 0; e < 8; ++e)
                o[e] = f2h((vals[it * 8 + e] - mu) * rs * gamma[c0 + e]
                           + beta[c0 + e]);
            *reinterpret_cast<f16x8*>(&T0[tp * 520 + c0]) =
                *reinterpret_cast<const f16x8*>(o);
        }
    }
    __syncthreads();
    // ---- Q = q @ Wq + bq : T0 -> T1 ----
    lds_gemm64(T0, T1, Wqb, bq, 0, lane, wv);
    __syncthreads();
    // ---- hid = relu(Q @ Wo1 + bo1) : T1 -> T0 ----
    lds_gemm64(T1, T0, Wo1b, bo1, 1, lane, wv);
    __syncthreads();
    // ---- off (waves 0-5: hid@Wo2, 96 cols) & logits (waves 6-7: Q@Wa) ----
    {
        int ml = lane & 15, quad = lane >> 4;
        int isLg = wv >= 6;
        int cb = isLg ? (wv - 6) : wv;             // 16-col block
        const u16* Tin = isLg ? T1 : T0;
        const u16* Wsm = isLg ? Wab : Wo2b;
        const float* bs = isLg ? ba : bo2;
        float* outg = isLg ? lgb : offb;
        int ldo = isLg ? 32 : 96;
        // preload wave's full 16-col x 512-K weight panel to registers
        const u16* Wp = Wsm + (size_t)cb * 8192 + (size_t)lane * 8;
        f16x8 wb[16];
#pragma unroll
        for (int kk = 0; kk < 16; kk++)
            wb[kk] = *reinterpret_cast<const f16x8*>(Wp + (size_t)kk * 512);
        float bia = bs[cb * 16 + ml];
        int tbase = blk * 64;
#pragma unroll
        for (int tg = 0; tg < 4; tg++) {
            f32x4 acc = (f32x4){0.f, 0.f, 0.f, 0.f};
            const u16* Ar = Tin + (tg * 16 + ml) * 520;
#pragma unroll
            for (int kk = 0; kk < 16; kk++) {
                f16x8 af = *reinterpret_cast<const f16x8*>(
                    Ar + (kk * 4 + quad) * 8);
                acc = __builtin_amdgcn_mfma_f32_16x16x32_f16(
                    af, wb[kk], acc, 0, 0, 0);
            }
#pragma unroll
            for (int rg = 0; rg < 4; rg++)
                outg[(size_t)(tbase + tg * 16 + quad * 4 + rg) * ldo
                     + cb * 16 + ml] = acc[rg] + bia;
        }
    }
}

// ---------------------------------------------------------------------------
// R20 sample_out: FUSED sample + out-GEMM. Both are token-local per
// 64-token tile: one sample wave produces all 512 channels of one token
// (8 heads x 8 lanes x 8 ch). Phase 1: 8 waves x 8 tokens each, gather ->
// T0 LDS (66.6 KB, no global qb roundtrip). Phase 2: lds_gemm64-style
// out-GEMM (Wout blocked, 4-deep asm B-ring, counted vmcnt), mode-2
// transposed fp32 float4 store. Kills: 1 dispatch, qb 16.4MB HBM write,
// and gemm_out's 8x A-reread (131MB L2). XCD-chunked bijective swizzle
// (q=31, r=2; m204) keeps each XCD's ~2000-token gather slab L2-local.
// p-loop fully unrolled: 32-deep load ILP at 2 waves/SIMD (256-VGPR ok).
// ---------------------------------------------------------------------------
__global__ __launch_bounds__(512, 2) void sample_out(
    const u16* __restrict__ vol, const float* __restrict__ offb,
    const float* __restrict__ lgb, const u16* __restrict__ Woutb,
    const float* __restrict__ bout, float* __restrict__ outp)
{
    __shared__ u16 T0[64 * 520];   // 66.6 KB
    int tid = threadIdx.x, lane = tid & 63, wv = tid >> 6;
    // bijective XCD chunking of 250 blocks (q=31, r=2)
    int orig = blockIdx.x;
    int xcd = orig & 7, slot = orig >> 3;
    int w = (xcd < 2 ? xcd * 32 : 64 + (xcd - 2) * 31) + slot;
    int tbase = w * 64;

    // ---- phase 1: gather. wave wv samples tokens tbase+wv*8 .. +8 ----
    {
        int h = lane >> 3, cl = lane & 7;
#pragma unroll 1
        for (int tt = 0; tt < 8; ++tt) {
            int trow = wv * 8 + tt;
            int bn = tbase + trow;
            int b = bn >= NTOK;
            int n = bn - b * NTOK;
            int y = n / 400;
            int r2 = n - y * 400;
            int x = r2 / 20;
            int z = r2 - x * 20;
            const float* op = offb + (size_t)bn * 96 + h * 12;
            const float* lp = lgb + (size_t)bn * 32 + h * 4;
            float l0 = lp[0], l1 = lp[1], l2 = lp[2], l3 = lp[3];
            float mx = fmaxf(fmaxf(l0, l1), fmaxf(l2, l3));
            float e0 = expf(l0 - mx), e1 = expf(l1 - mx);
            float e2 = expf(l2 - mx), e3 = expf(l3 - mx);
            float inv = 1.f / (e0 + e1 + e2 + e3);
            float at[4] = {e0 * inv, e1 * inv, e2 * inv, e3 * inv};
            const u16* volb = vol + b * (NTOK * C_DIM) + h * HDIM + cl * 8;
            h2 acc0 = (h2)(_Float16)0, acc1 = acc0, acc2 = acc0, acc3 = acc0;
#pragma unroll
            for (int p = 0; p < 4; p++) {
                float o0 = fminf(fmaxf(op[p * 3 + 0], -3.f), 3.f);
                float o1 = fminf(fmaxf(op[p * 3 + 1], -3.f), 3.f);
                float o2 = fminf(fmaxf(op[p * 3 + 2], -3.f), 3.f);
                float ix = fminf(fmaxf((float)y + o0, 0.f), 19.f);  // W axis
                float iy = fminf(fmaxf((float)x + o1, 0.f), 19.f);  // H axis
                float iz = fminf(fmaxf((float)z + o2, 0.f), 19.f);  // D axis
                float xf = floorf(ix), yf = floorf(iy), zf = floorf(iz);
                float fx = ix - xf, fy = iy - yf, fz = iz - zf;
                int x0 = (int)xf, y0 = (int)yf, z0 = (int)zf;
                int x1 = imin(x0 + 1, 19), y1 = imin(y0 + 1, 19);
                int z1 = imin(z0 + 1, 19);
                int s00 = y0 * 400 + x0 * 20, s01 = y0 * 400 + x1 * 20;
                int s10 = y1 * 400 + x0 * 20, s11 = y1 * 400 + x1 * 20;
                uint4 v000 = *(const uint4*)(volb + (s00 + z0) * C_DIM);
                uint4 v001 = *(const uint4*)(volb + (s01 + z0) * C_DIM);
                uint4 v010 = *(const uint4*)(volb + (s10 + z0) * C_DIM);
                uint4 v011 = *(const uint4*)(volb + (s11 + z0) * C_DIM);
                uint4 v100 = *(const uint4*)(volb + (s00 + z1) * C_DIM);
                uint4 v101 = *(const uint4*)(volb + (s01 + z1) * C_DIM);
                uint4 v110 = *(const uint4*)(volb + (s10 + z1) * C_DIM);
                uint4 v111 = *(const uint4*)(volb + (s11 + z1) * C_DIM);
                float wz0 = (1.f - fz) * at[p], wz1 = fz * at[p];
                float w00 = wz0 * (1.f - fy), w01 = wz0 * fy;
                float w10 = wz1 * (1.f - fy), w11 = wz1 * fy;
                float gx0 = 1.f - fx;
                float cw[8] = { w00 * gx0, w00 * fx, w01 * gx0, w01 * fx,
                                w10 * gx0, w10 * fx, w11 * gx0, w11 * fx };
                const uint4* cv[8] = { &v000, &v001, &v010, &v011,
                                       &v100, &v101, &v110, &v111 };
#pragma unroll
                for (int c = 0; c < 8; c++) {
                    _Float16 wh = (_Float16)cw[c];
                    h2 w2; w2.x = wh; w2.y = wh;
                    uint4 d = *cv[c];
                    acc0 += __builtin_bit_cast(h2, d.x) * w2;
                    acc1 += __builtin_bit_cast(h2, d.y) * w2;
                    acc2 += __builtin_bit_cast(h2, d.z) * w2;
                    acc3 += __builtin_bit_cast(h2, d.w) * w2;
                }
            }
            uint4 o;
            o.x = __builtin_bit_cast(unsigned, acc0);
            o.y = __builtin_bit_cast(unsigned, acc1);
            o.z = __builtin_bit_cast(unsigned, acc2);
            o.w = __builtin_bit_cast(unsigned, acc3);
            *reinterpret_cast<uint4*>(&T0[trow * 520 + h * HDIM + cl * 8]) = o;
        }
    }
    __syncthreads();

    // ---- phase 2: out = (T0 @ Wout + bout)^T, wave owns 64-col slice ----
    {
        int ml = lane & 15, quad = lane >> 4;
        int c0 = wv * 64;
        const u16* Bp = Woutb + (size_t)(c0 >> 4) * 8192 + (size_t)lane * 8;

        f32x4 acc[4][4];
#pragma unroll
        for (int t = 0; t < 4; t++)
#pragma unroll
            for (int j = 0; j < 4; j++) acc[t][j] = (f32x4){0.f, 0.f, 0.f, 0.f};

        f32x4 bfr[4][4];
#pragma unroll
        for (int kb = 0; kb < 3; kb++)
#pragma unroll
            for (int j = 0; j < 4; j++)
                bfr[kb][j] = agload16(Bp + (size_t)j * 8192 + kb * 512);

#pragma unroll
        for (int kk = 0; kk < 16; kk++) {
            if (kk + 3 < 16) {
#pragma unroll
                for (int j = 0; j < 4; j++)
                    bfr[(kk + 3) & 3][j] = agload16(
                        Bp + (size_t)j * 8192 + (kk + 3) * 512);
            }
            f16x8 a[4];
#pragma unroll
            for (int t = 0; t < 4; t++)
                a[t] = *reinterpret_cast<const f16x8*>(
                    T0 + (t * 16 + ml) * 520 + (kk * 4 + quad) * 8);
            if (kk < 13)       VMWAIT(12);
            else if (kk == 13) VMWAIT(8);
            else if (kk == 14) VMWAIT(4);
            else               VMWAIT(0);
#pragma unroll
            for (int j = 0; j < 4; j++) {
                f16x8 bj = __builtin_bit_cast(f16x8, bfr[kk & 3][j]);
#pragma unroll
                for (int t = 0; t < 4; t++)
                    acc[t][j] = __builtin_amdgcn_mfma_f32_16x16x32_f16(
                        a[t], bj, acc[t][j], 0, 0, 0);
            }
        }

        // epilogue: out[(bb*512+col)*8000 + tok], 4 consec tokens = float4
        int bb = tbase >= NTOK;
        int tloc = tbase - bb * NTOK;
#pragma unroll
        for (int t = 0; t < 4; t++)
#pragma unroll
            for (int j = 0; j < 4; j++) {
                int col = c0 + j * 16 + ml;
                float bia = bout[col];
                float4 st;
                st.x = acc[t][j][0] + bia;
                st.y = acc[t][j][1] + bia;
                st.z = acc[t][j][2] + bia;
                st.w = acc[t][j][3] + bia;
                *reinterpret_cast<float4*>(
                    outp + ((size_t)(bb * 512 + col)) * 8000
                         + tloc + t * 16 + quad * 4) = st;
            }
    }
}

// ---------------------------------------------------------------------------
// Launch: 3 dispatches (was 5).
// ---------------------------------------------------------------------------
extern "C" void kernel_launch(void* const* d_in, const int* in_sizes, int n_in,
                              void* d_out, int out_size, void* d_ws, size_t ws_size,
                              hipStream_t stream)
{
    const float* f_query = (const float*)d_in[0];
    const float* f_kv    = (const float*)d_in[1];
    const float* ln_g    = (const float*)d_in[2];
    const float* ln_b    = (const float*)d_in[3];
    const float* Wq      = (const float*)d_in[4];
    const float* bq      = (const float*)d_in[5];
    const float* Wo1     = (const float*)d_in[6];
    const float* bo1     = (const float*)d_in[7];
    const float* Wo2     = (const float*)d_in[8];
    const float* bo2     = (const float*)d_in[9];
    const float* Wa      = (const float*)d_in[10];
    const float* ba      = (const float*)d_in[11];
    const float* Wout    = (const float*)d_in[12];
    const float* bout    = (const float*)d_in[13];
    float* out = (float*)d_out;

    float* ws = (float*)d_ws;
    float* offb = ws;                     // 1,536,000 f
    float* lgb  = ws + 1536000;           //   512,000 f
    u16* kvT   = (u16*)(ws + 2048000);    // 16000x512 (f16 channels-last)
    u16* WqT   = kvT + 16384000;          // 512x512 blocked
    u16* Wo1T  = WqT + 262144;            // 512x512 blocked
    u16* WoutT = Wo1T + 262144;           // 512x512 blocked
    u16* Wo2T  = WoutT + 262144;          // 128x512 blocked (96 valid)
    u16* WaT   = Wo2T + 65536;            // 128x512 blocked (32 valid)

    dim3 blk(256);
    dim3 blk512(512);
    // prep: f_kv transpose + all weight converts, one dispatch
    prep_all<<<dim3(9280), blk, 0, stream>>>(
        f_kv, kvT, Wq, WqT, Wo1, Wo1T, Wout, WoutT, Wo2, Wo2T, Wa, WaT);
    // fused LN -> Q -> hid -> off/logits (token-local chain)
    mlp_fused<<<dim3(250), blk512, 0, stream>>>(
        f_query, ln_g, ln_b, WqT, bq, Wo1T, bo1, Wo2T, bo2, WaT, ba,
        offb, lgb);
    // fused sample/softmax/einsum + out-GEMM (token-local chain)
    sample_out<<<dim3(250), blk512, 0, stream>>>(
        kvT, offb, lgb, WoutT, bout, out);
}